// Round 1
// baseline (664.054 us; speedup 1.0000x reference)
//
#include <hip/hip_runtime.h>
#include <math.h>

#define NB 32
#define DM 128
#define SL 2048
#define WIN 64

// ---------------------------------------------------------------------------
// ws layout (floats):
//   sq  : NB*SL*DM   sigmoid(q); overwritten in-place with y by band_kernel
//   ek  : NB*SL*DM   exp(k)   (un-normalized; max cancels in num/den)
//   ekv : NB*SL*DM   exp(k)*v
//   epb : SL*128     e^{pos_bias[i][j]}-1 for jj=j-i+63 in [0,127), 0 outside
//   Sk  : NB*DM      sum_l ek
//   Skv : NB*DM      sum_l ekv
//   Pk  : NB*16*DM   partial sums
//   Pkv : NB*16*DM
// ---------------------------------------------------------------------------

// QKV projection: q/k/v[n,l,d] = sum_c x[n,c,l] * W[c,d] + b[d]
// One block: (n, 64 l's). xs tile staged in LDS; W read coalesced (L2-served).
__global__ __launch_bounds__(256) void qkv_kernel(
    const float* __restrict__ x,
    const float* __restrict__ Wq, const float* __restrict__ bq,
    const float* __restrict__ Wk, const float* __restrict__ bk,
    const float* __restrict__ Wv, const float* __restrict__ bv,
    float* __restrict__ sq, float* __restrict__ ek, float* __restrict__ ekv)
{
    __shared__ __align__(16) float xs[DM][64];
    const int n  = blockIdx.y;
    const int l0 = blockIdx.x * 64;
    const int tid = threadIdx.x;

    #pragma unroll
    for (int w = 0; w < 32; ++w) {
        int idx = w * 256 + tid;
        int c = idx >> 6, lo = idx & 63;
        xs[c][lo] = x[(n * DM + c) * SL + l0 + lo];
    }
    __syncthreads();

    const int d  = tid & 127;
    const int lh = tid >> 7;
    const float bqv = bq[d], bkv = bk[d], bvv = bv[d];

    for (int chunk = 0; chunk < 2; ++chunk) {
        const int lobase = lh * 32 + chunk * 16;
        float aq[16], ak[16], av[16];
        #pragma unroll
        for (int j = 0; j < 16; ++j) { aq[j] = bqv; ak[j] = bkv; av[j] = bvv; }

        const float* pq = Wq + d;
        const float* pk = Wk + d;
        const float* pv = Wv + d;
        for (int c = 0; c < DM; ++c) {
            float wq = pq[c * DM];
            float wk = pk[c * DM];
            float wv = pv[c * DM];
            const float4* xr = (const float4*)&xs[c][lobase];
            #pragma unroll
            for (int q4 = 0; q4 < 4; ++q4) {
                float4 xv = xr[q4];
                aq[q4*4+0] += xv.x * wq; ak[q4*4+0] += xv.x * wk; av[q4*4+0] += xv.x * wv;
                aq[q4*4+1] += xv.y * wq; ak[q4*4+1] += xv.y * wk; av[q4*4+1] += xv.y * wv;
                aq[q4*4+2] += xv.z * wq; ak[q4*4+2] += xv.z * wk; av[q4*4+2] += xv.z * wv;
                aq[q4*4+3] += xv.w * wq; ak[q4*4+3] += xv.w * wk; av[q4*4+3] += xv.w * wv;
            }
        }

        #pragma unroll
        for (int j = 0; j < 16; ++j) {
            int l = l0 + lobase + j;
            int idx = (n * SL + l) * DM + d;
            sq[idx] = 1.0f / (1.0f + __expf(-aq[j]));
            float e = __expf(ak[j]);
            ek[idx]  = e;
            ekv[idx] = e * av[j];
        }
    }
}

// Stage 1 totals: per (n, 128-l segment) partial sums of ek / ekv over l.
__global__ __launch_bounds__(256) void totals_partial(
    const float* __restrict__ ek, const float* __restrict__ ekv,
    float* __restrict__ Pk, float* __restrict__ Pkv)
{
    const int n = blockIdx.y, seg = blockIdx.x;
    const int tid = threadIdx.x;
    const int d = tid & 127, h = tid >> 7;
    float sk = 0.f, skv = 0.f;
    const int l0 = seg * 128;
    for (int l = l0 + h; l < l0 + 128; l += 2) {
        int idx = (n * SL + l) * DM + d;
        sk  += ek[idx];
        skv += ekv[idx];
    }
    __shared__ float rk[256], rkv[256];
    rk[tid] = sk; rkv[tid] = skv;
    __syncthreads();
    if (h == 0) {
        Pk [(n * 16 + seg) * DM + d] = rk[d]  + rk[128 + d];
        Pkv[(n * 16 + seg) * DM + d] = rkv[d] + rkv[128 + d];
    }
}

// Stage 2 totals: reduce the 16 segments.
__global__ __launch_bounds__(128) void totals_final(
    const float* __restrict__ Pk, const float* __restrict__ Pkv,
    float* __restrict__ Sk, float* __restrict__ Skv)
{
    const int n = blockIdx.x;
    const int d = threadIdx.x;
    float sk = 0.f, skv = 0.f;
    #pragma unroll
    for (int seg = 0; seg < 16; ++seg) {
        sk  += Pk [(n * 16 + seg) * DM + d];
        skv += Pkv[(n * 16 + seg) * DM + d];
    }
    Sk [n * DM + d] = sk;
    Skv[n * DM + d] = skv;
}

// Banded weights: epb[i][jj] = exp(pos_bias[i][i+jj-63]) - 1 (0 if outside).
__global__ __launch_bounds__(256) void epb_kernel(
    const float* __restrict__ pos_bias, float* __restrict__ epb)
{
    int e = blockIdx.x * 256 + threadIdx.x;
    int i = e >> 7, jj = e & 127;
    int j = i + jj - 63;
    float val = 0.f;
    if (jj < 127 && j >= 0 && j < SL)
        val = __expf(pos_bias[i * SL + j]) - 1.0f;
    epb[i * 128 + jj] = val;
}

// Band correction + ratio + sigmoid gate. y written in-place over sq.
__global__ __launch_bounds__(256) void band_kernel(
    const float* __restrict__ ek, const float* __restrict__ ekv,
    const float* __restrict__ epb,
    const float* __restrict__ Sk, const float* __restrict__ Skv,
    float* __restrict__ sqy)
{
    const int n  = blockIdx.y;
    const int dg = threadIdx.x & 31;   // d4 = dg*4
    const int il = threadIdx.x >> 5;   // 8 i's per block
    const int i  = blockIdx.x * 8 + il;
    const int d4 = dg * 4;

    float4 accd = *(const float4*)(Sk  + n * DM + d4);
    float4 accn = *(const float4*)(Skv + n * DM + d4);

    int jjlo = 63 - i;       if (jjlo < 0)   jjlo = 0;
    int jjhi = (SL - 1) + 63 - i; if (jjhi > 126) jjhi = 126;

    const float* pw = epb + i * 128 + jjlo;
    int base = (n * SL + (i - 63 + jjlo)) * DM + d4;

    for (int jj = jjlo; jj <= jjhi; ++jj) {
        float  w   = *pw++;
        float4 e4  = *(const float4*)(ek  + base);
        float4 kv4 = *(const float4*)(ekv + base);
        accd.x += w * e4.x;  accd.y += w * e4.y;  accd.z += w * e4.z;  accd.w += w * e4.w;
        accn.x += w * kv4.x; accn.y += w * kv4.y; accn.z += w * kv4.z; accn.w += w * kv4.w;
        base += DM;
    }

    const int idx = (n * SL + i) * DM + d4;
    float4 s = *(const float4*)(sqy + idx);
    float4 yv;
    yv.x = s.x * accn.x / accd.x;
    yv.y = s.y * accn.y / accd.y;
    yv.z = s.z * accn.z / accd.z;
    yv.w = s.w * accn.w / accd.w;
    *(float4*)(sqy + idx) = yv;
}

// Output projection: out[n,c,l] = sum_d y[n,l,d] * Wo[d,c] + bo[c]
__global__ __launch_bounds__(256) void out_kernel(
    const float* __restrict__ y, const float* __restrict__ Wo,
    const float* __restrict__ bo, float* __restrict__ out)
{
    __shared__ __align__(16) float ys[64][129];   // +1 pad: kills bank conflicts
    const int n  = blockIdx.y;
    const int l0 = blockIdx.x * 64;
    const int tid = threadIdx.x;

    #pragma unroll
    for (int w = 0; w < 32; ++w) {
        int idx = w * 256 + tid;
        int ll = idx >> 7, d = idx & 127;
        ys[ll][d] = y[(n * SL + l0 + ll) * DM + d];
    }
    __syncthreads();

    const int ll = tid & 63;
    const int cg = tid >> 6;
    for (int chunk = 0; chunk < 4; ++chunk) {
        const int c0 = cg * 32 + chunk * 8;
        float acc[8];
        #pragma unroll
        for (int j = 0; j < 8; ++j) acc[j] = bo[c0 + j];
        for (int dd = 0; dd < DM; ++dd) {
            float yv = ys[ll][dd];
            const float4* wr = (const float4*)(Wo + dd * DM + c0);
            float4 w0 = wr[0], w1 = wr[1];
            acc[0] += yv * w0.x; acc[1] += yv * w0.y;
            acc[2] += yv * w0.z; acc[3] += yv * w0.w;
            acc[4] += yv * w1.x; acc[5] += yv * w1.y;
            acc[6] += yv * w1.z; acc[7] += yv * w1.w;
        }
        #pragma unroll
        for (int j = 0; j < 8; ++j)
            out[(n * DM + c0 + j) * SL + l0 + ll] = acc[j];
    }
}

extern "C" void kernel_launch(void* const* d_in, const int* in_sizes, int n_in,
                              void* d_out, int out_size, void* d_ws, size_t ws_size,
                              hipStream_t stream)
{
    const float* x        = (const float*)d_in[0];
    const float* Wq       = (const float*)d_in[1];
    const float* bq       = (const float*)d_in[2];
    const float* Wk       = (const float*)d_in[3];
    const float* bk       = (const float*)d_in[4];
    const float* Wv       = (const float*)d_in[5];
    const float* bv       = (const float*)d_in[6];
    const float* Wo       = (const float*)d_in[7];
    const float* bo       = (const float*)d_in[8];
    const float* pos_bias = (const float*)d_in[9];
    float* out = (float*)d_out;

    float* ws  = (float*)d_ws;
    const size_t NLD = (size_t)NB * SL * DM;
    float* sq  = ws;
    float* ek  = sq  + NLD;
    float* ekv = ek  + NLD;
    float* epb = ekv + NLD;
    float* Sk  = epb + (size_t)SL * 128;
    float* Skv = Sk  + (size_t)NB * DM;
    float* Pk  = Skv + (size_t)NB * DM;
    float* Pkv = Pk  + (size_t)NB * 16 * DM;

    qkv_kernel   <<<dim3(SL / 64, NB), 256, 0, stream>>>(x, Wq, bq, Wk, bk, Wv, bv, sq, ek, ekv);
    totals_partial<<<dim3(16, NB),     256, 0, stream>>>(ek, ekv, Pk, Pkv);
    totals_final <<<dim3(NB),          128, 0, stream>>>(Pk, Pkv, Sk, Skv);
    epb_kernel   <<<dim3(SL * 128 / 256), 256, 0, stream>>>(pos_bias, epb);
    band_kernel  <<<dim3(SL / 8, NB),  256, 0, stream>>>(ek, ekv, epb, Sk, Skv, sq);
    out_kernel   <<<dim3(SL / 64, NB), 256, 0, stream>>>(sq, Wo, bo, out);
}

// Round 2
// 489.300 us; speedup vs baseline: 1.3572x; 1.3572x over previous
//
#include <hip/hip_runtime.h>
#include <math.h>

#define NB 32
#define DM 128
#define SL 2048
#define WIN 64
#define TI 64          // i's per band block
#define EPB_STRIDE 144 // 128 band cols + 8 zero pad each side

// ---------------------------------------------------------------------------
// ws layout (floats):
//   sq   : NB*SL*DM     sigmoid(q); overwritten in-place with y by band_kernel
//   ek   : NB*SL*DM     exp(k)   (un-normalized; max cancels in num/den)
//   ekv  : NB*SL*DM     exp(k)*v
//   epbp : SL*144       padded e^{pb}-1 band table (8 zero cols each side)
//   Sk   : NB*DM        sum_l ek
//   Skv  : NB*DM        sum_l ekv
//   Pk   : NB*32*DM     per-qkv-block partial sums
//   Pkv  : NB*32*DM
// ---------------------------------------------------------------------------

// QKV projection + fused ek/ekv partial sums.
__global__ __launch_bounds__(256) void qkv_kernel(
    const float* __restrict__ x,
    const float* __restrict__ Wq, const float* __restrict__ bq,
    const float* __restrict__ Wk, const float* __restrict__ bk,
    const float* __restrict__ Wv, const float* __restrict__ bv,
    float* __restrict__ sq, float* __restrict__ ek, float* __restrict__ ekv,
    float* __restrict__ Pk, float* __restrict__ Pkv)
{
    __shared__ __align__(16) float xs[DM][64];
    __shared__ float rk[256], rkv[256];
    const int n  = blockIdx.y;
    const int bx = blockIdx.x;
    const int l0 = bx * 64;
    const int tid = threadIdx.x;

    #pragma unroll
    for (int w = 0; w < 32; ++w) {
        int idx = w * 256 + tid;
        int c = idx >> 6, lo = idx & 63;
        xs[c][lo] = x[(n * DM + c) * SL + l0 + lo];
    }
    __syncthreads();

    const int d  = tid & 127;
    const int lh = tid >> 7;
    const float bqv = bq[d], bkv = bk[d], bvv = bv[d];

    float sk = 0.f, skv = 0.f;

    for (int chunk = 0; chunk < 2; ++chunk) {
        const int lobase = lh * 32 + chunk * 16;
        float aq[16], ak[16], av[16];
        #pragma unroll
        for (int j = 0; j < 16; ++j) { aq[j] = bqv; ak[j] = bkv; av[j] = bvv; }

        const float* pq = Wq + d;
        const float* pk = Wk + d;
        const float* pv = Wv + d;
        for (int c = 0; c < DM; ++c) {
            float wq = pq[c * DM];
            float wk = pk[c * DM];
            float wv = pv[c * DM];
            const float4* xr = (const float4*)&xs[c][lobase];
            #pragma unroll
            for (int q4 = 0; q4 < 4; ++q4) {
                float4 xv = xr[q4];
                aq[q4*4+0] += xv.x * wq; ak[q4*4+0] += xv.x * wk; av[q4*4+0] += xv.x * wv;
                aq[q4*4+1] += xv.y * wq; ak[q4*4+1] += xv.y * wk; av[q4*4+1] += xv.y * wv;
                aq[q4*4+2] += xv.z * wq; ak[q4*4+2] += xv.z * wk; av[q4*4+2] += xv.z * wv;
                aq[q4*4+3] += xv.w * wq; ak[q4*4+3] += xv.w * wk; av[q4*4+3] += xv.w * wv;
            }
        }

        #pragma unroll
        for (int j = 0; j < 16; ++j) {
            int l = l0 + lobase + j;
            int idx = (n * SL + l) * DM + d;
            sq[idx] = 1.0f / (1.0f + __expf(-aq[j]));
            float e = __expf(ak[j]);
            float z = e * av[j];
            ek[idx]  = e;
            ekv[idx] = z;
            sk  += e;
            skv += z;
        }
    }

    rk[tid] = sk; rkv[tid] = skv;
    __syncthreads();
    if (tid < 128) {
        Pk [(n * 32 + bx) * DM + tid] = rk[tid]  + rk[128 + tid];
        Pkv[(n * 32 + bx) * DM + tid] = rkv[tid] + rkv[128 + tid];
    }
}

// Reduce the 32 per-block segments to full-L sums.
__global__ __launch_bounds__(128) void totals_final(
    const float* __restrict__ Pk, const float* __restrict__ Pkv,
    float* __restrict__ Sk, float* __restrict__ Skv)
{
    const int n = blockIdx.x;
    const int d = threadIdx.x;
    float sk = 0.f, skv = 0.f;
    #pragma unroll
    for (int seg = 0; seg < 32; ++seg) {
        sk  += Pk [(n * 32 + seg) * DM + d];
        skv += Pkv[(n * 32 + seg) * DM + d];
    }
    Sk [n * DM + d] = sk;
    Skv[n * DM + d] = skv;
}

// Padded banded weights: epbp[i][col] for col in [0,144), band coord jj=col-8.
// epbp = exp(pos_bias[i][i+jj-63]) - 1 inside band (jj in [0,127), j valid), else 0.
__global__ __launch_bounds__(256) void epb_kernel(
    const float* __restrict__ pos_bias, float* __restrict__ epbp)
{
    const int i = blockIdx.x;
    const int col = threadIdx.x;
    if (col >= EPB_STRIDE) return;
    int jj = col - 8;
    int j = i + jj - 63;
    float val = 0.f;
    if (jj >= 0 && jj < 127 && j >= 0 && j < SL)
        val = __expf(pos_bias[i * SL + j]) - 1.0f;
    epbp[i * EPB_STRIDE + col] = val;
}

// Band correction + ratio + sigmoid gate. 8 i's per thread for register reuse
// of the z-loads; weights broadcast from LDS. XCD-swizzled block mapping.
__global__ __launch_bounds__(256, 4) void band_kernel(
    const float* __restrict__ ek, const float* __restrict__ ekv,
    const float* __restrict__ epbp,
    const float* __restrict__ Sk, const float* __restrict__ Skv,
    float* __restrict__ sqy)
{
    __shared__ float wlds[TI * EPB_STRIDE];   // 64 x 144 = 36 KB

    // XCD-aware swizzle: each XCD gets 4 consecutive 64-i chunks of one n,
    // i.e. a contiguous 256-i range -> its L2 streams ~1/8 of the data + halo.
    const int lid  = blockIdx.x;          // 0..1023
    const int xcd  = lid & 7;
    const int slot = lid >> 3;            // 0..127
    const int n    = slot >> 2;           // 0..31
    const int sub  = slot & 3;
    const int ibase = (xcd * 4 + sub) * TI;

    for (int t = threadIdx.x; t < TI * EPB_STRIDE; t += 256)
        wlds[t] = epbp[ibase * EPB_STRIDE + t];
    __syncthreads();

    const int dg = threadIdx.x & 31;
    const int il = threadIdx.x >> 5;      // 8 groups of 8 i's
    const int d4 = dg * 4;
    const int i0 = ibase + il * 8;

    const float4 Sk4  = *(const float4*)(Sk  + n * DM + d4);
    const float4 Skv4 = *(const float4*)(Skv + n * DM + d4);
    float4 accd[8], accn[8];
    #pragma unroll
    for (int ii = 0; ii < 8; ++ii) { accd[ii] = Sk4; accn[ii] = Skv4; }

    int jlo = i0 - (WIN - 1);      if (jlo < 0) jlo = 0;
    int jhi = i0 + 7 + (WIN - 1);  if (jhi > SL - 1) jhi = SL - 1;

    const float* pe = ek  + ((size_t)n * SL + jlo) * DM + d4;
    const float* pv = ekv + ((size_t)n * SL + jlo) * DM + d4;
    // row (il*8+ii), col (jrel - ii + 8):  wbase[ii*144 + jrel - ii]
    const float* wbase = wlds + (il * 8) * EPB_STRIDE + 8;

    for (int j = jlo; j <= jhi; ++j) {
        float4 e4  = *(const float4*)pe;
        float4 kv4 = *(const float4*)pv;
        pe += DM; pv += DM;
        const int jrel = j - i0 + (WIN - 1);
        #pragma unroll
        for (int ii = 0; ii < 8; ++ii) {
            float w = wbase[ii * EPB_STRIDE + jrel - ii];
            accd[ii].x += w * e4.x;  accd[ii].y += w * e4.y;
            accd[ii].z += w * e4.z;  accd[ii].w += w * e4.w;
            accn[ii].x += w * kv4.x; accn[ii].y += w * kv4.y;
            accn[ii].z += w * kv4.z; accn[ii].w += w * kv4.w;
        }
    }

    #pragma unroll
    for (int ii = 0; ii < 8; ++ii) {
        const size_t idx = ((size_t)n * SL + i0 + ii) * DM + d4;
        float4 s = *(const float4*)(sqy + idx);
        float4 yv;
        yv.x = s.x * accn[ii].x / accd[ii].x;
        yv.y = s.y * accn[ii].y / accd[ii].y;
        yv.z = s.z * accn[ii].z / accd[ii].z;
        yv.w = s.w * accn[ii].w / accd[ii].w;
        *(float4*)(sqy + idx) = yv;
    }
}

// Output projection: out[n,c,l] = sum_d y[n,l,d] * Wo[d,c] + bo[c]
__global__ __launch_bounds__(256) void out_kernel(
    const float* __restrict__ y, const float* __restrict__ Wo,
    const float* __restrict__ bo, float* __restrict__ out)
{
    __shared__ __align__(16) float ys[64][129];
    const int n  = blockIdx.y;
    const int l0 = blockIdx.x * 64;
    const int tid = threadIdx.x;

    #pragma unroll
    for (int w = 0; w < 32; ++w) {
        int idx = w * 256 + tid;
        int ll = idx >> 7, d = idx & 127;
        ys[ll][d] = y[(n * SL + l0 + ll) * DM + d];
    }
    __syncthreads();

    const int ll = tid & 63;
    const int cg = tid >> 6;
    for (int chunk = 0; chunk < 4; ++chunk) {
        const int c0 = cg * 32 + chunk * 8;
        float acc[8];
        #pragma unroll
        for (int j = 0; j < 8; ++j) acc[j] = bo[c0 + j];
        for (int dd = 0; dd < DM; ++dd) {
            float yv = ys[ll][dd];
            const float4* wr = (const float4*)(Wo + dd * DM + c0);
            float4 w0 = wr[0], w1 = wr[1];
            acc[0] += yv * w0.x; acc[1] += yv * w0.y;
            acc[2] += yv * w0.z; acc[3] += yv * w0.w;
            acc[4] += yv * w1.x; acc[5] += yv * w1.y;
            acc[6] += yv * w1.z; acc[7] += yv * w1.w;
        }
        #pragma unroll
        for (int j = 0; j < 8; ++j)
            out[(n * DM + c0 + j) * SL + l0 + ll] = acc[j];
    }
}

extern "C" void kernel_launch(void* const* d_in, const int* in_sizes, int n_in,
                              void* d_out, int out_size, void* d_ws, size_t ws_size,
                              hipStream_t stream)
{
    const float* x        = (const float*)d_in[0];
    const float* Wq       = (const float*)d_in[1];
    const float* bq       = (const float*)d_in[2];
    const float* Wk       = (const float*)d_in[3];
    const float* bk       = (const float*)d_in[4];
    const float* Wv       = (const float*)d_in[5];
    const float* bv       = (const float*)d_in[6];
    const float* Wo       = (const float*)d_in[7];
    const float* bo       = (const float*)d_in[8];
    const float* pos_bias = (const float*)d_in[9];
    float* out = (float*)d_out;

    float* ws  = (float*)d_ws;
    const size_t NLD = (size_t)NB * SL * DM;
    float* sq   = ws;
    float* ek   = sq   + NLD;
    float* ekv  = ek   + NLD;
    float* epbp = ekv  + NLD;
    float* Sk   = epbp + (size_t)SL * EPB_STRIDE;
    float* Skv  = Sk   + (size_t)NB * DM;
    float* Pk   = Skv  + (size_t)NB * DM;
    float* Pkv  = Pk   + (size_t)NB * 32 * DM;

    qkv_kernel  <<<dim3(SL / 64, NB), 256, 0, stream>>>(x, Wq, bq, Wk, bk, Wv, bv,
                                                        sq, ek, ekv, Pk, Pkv);
    totals_final<<<dim3(NB),          128, 0, stream>>>(Pk, Pkv, Sk, Skv);
    epb_kernel  <<<dim3(SL),          256, 0, stream>>>(pos_bias, epbp);
    band_kernel <<<dim3(NB * SL / TI), 256, 0, stream>>>(ek, ekv, epbp, Sk, Skv, sq);
    out_kernel  <<<dim3(SL / 64, NB), 256, 0, stream>>>(sq, Wo, bo, out);
}

// Round 3
// 386.073 us; speedup vs baseline: 1.7200x; 1.2674x over previous
//
#include <hip/hip_runtime.h>
#include <math.h>

#define NB 32
#define DM 128
#define SL 2048
#define WIN 64

typedef __attribute__((ext_vector_type(8))) short bf16x8;
typedef __attribute__((ext_vector_type(4))) float f32x4;

__device__ inline ushort bf16_rne(float f) {
    union { float f; unsigned u; } v; v.f = f;
    unsigned u = v.u;
    return (ushort)((u + 0x7FFFu + ((u >> 16) & 1u)) >> 16);
}
__device__ inline float bf16_to_f(ushort h) {
    union { unsigned u; float f; } v; v.u = ((unsigned)h) << 16;
    return v.f;
}

// ---------------------------------------------------------------------------
// ws layout (floats):
//   sq   : NB*SL*DM   sigmoid(q); overwritten in-place with y by band_kernel
//   ek   : NB*SL*DM   exp(k)
//   ekv  : NB*SL*DM   exp(k)*v
//   T    : 32*8*184*8 strided-band weight table  T[b][il][col][k]
//   Sk   : NB*DM      sum_l ek
//   Skv  : NB*DM      sum_l ekv
//   Pk   : NB*32*DM   per-qkv-block partial sums
//   Pkv  : NB*32*DM
//   Wh   : 3*128*128 bf16 (as ushort) fragment-ordered hi parts (12288 floats)
//   Wl   : same, lo parts
// ---------------------------------------------------------------------------

// Pack Wq/Wk/Wv into MFMA B-fragment order, split hi/lo bf16.
// B[k=c][n=d] frag: lane holds k = ks*32 + (lane>>4)*8 + j, n = dt*16 + (lane&15).
// Table idx (shorts) = (((mat*8+dt)*4+ks)*64 + lane)*8 + j = id*512 + t.
__global__ __launch_bounds__(512) void build_W(
    const float* __restrict__ Wq, const float* __restrict__ Wk,
    const float* __restrict__ Wv, ushort* __restrict__ Wh, ushort* __restrict__ Wl)
{
    const int id = blockIdx.x;            // (mat*8+dt)*4+ks, 0..95
    const int mat = id >> 5;
    const int dt = (id & 31) >> 2, ks = id & 3;
    const int t = threadIdx.x;            // lane*8 + j
    const int lane = t >> 3, j = t & 7;
    const int c = ks * 32 + (lane >> 4) * 8 + j;
    const int d = dt * 16 + (lane & 15);
    const float* W = (mat == 0) ? Wq : ((mat == 1) ? Wk : Wv);
    float w = W[c * DM + d];
    ushort h = bf16_rne(w);
    Wh[(size_t)id * 512 + t] = h;
    Wl[(size_t)id * 512 + t] = bf16_rne(w - bf16_to_f(h));
}

// Strided-band weight table: for thread (b, il) handling i = b*64+il+8k,
// col = j - (b*64+il) + 63 in [0,184): T[...] = e^{pb[i][j]}-1 inside band else 0.
__global__ __launch_bounds__(256) void build_T(
    const float* __restrict__ pos_bias, float* __restrict__ T)
{
    const int b = blockIdx.x >> 3, il = blockIdx.x & 7;
    const int i0 = b * 64 + il;
    for (int t = threadIdx.x; t < 184 * 8; t += 256) {
        const int col = t >> 3, k = t & 7;
        const int i = i0 + 8 * k;
        const int j = i0 + col - 63;
        const int jj = col - 8 * k;               // = j - i + 63
        float val = 0.f;
        if (jj >= 0 && jj < 127 && j >= 0 && j < SL)
            val = __expf(pos_bias[(size_t)i * SL + j]) - 1.f;
        T[((size_t)(b * 8 + il) * 184 + col) * 8 + k] = val;
    }
}

// QKV projection via split-bf16 MFMA (16x16x32). Block = (n, 64 l's), 4 waves.
// Wave w covers d in [w*32, w*32+32); acc[mat][dt][lt] bias-initialized.
__global__ __launch_bounds__(256, 2) void qkv_kernel(
    const float* __restrict__ x,
    const ushort* __restrict__ Wh, const ushort* __restrict__ Wl,
    const float* __restrict__ bq, const float* __restrict__ bk,
    const float* __restrict__ bv,
    float* __restrict__ sq, float* __restrict__ ek, float* __restrict__ ekv,
    float* __restrict__ Pk, float* __restrict__ Pkv)
{
    __shared__ ushort Ah[64 * 128];   // frag order: ((lt*4+ks)*64+lane)*8+j
    __shared__ ushort Al[64 * 128];
    const int n = blockIdx.y, bx = blockIdx.x, l0 = bx * 64;
    const int tid = threadIdx.x;

    // Stage x tile -> split bf16, written directly in A-fragment order.
    {
        const int lo = tid & 63;
        const int cq = tid >> 6;              // 0..3
        const int l  = l0 + lo;
        for (int cc = 0; cc < 8; ++cc) {
            const int c0 = cc * 16 + cq * 4;  // c0 & 7 in {0,4}
            float xv[4]; ushort hh[4], ll[4];
            #pragma unroll
            for (int u = 0; u < 4; ++u)
                xv[u] = x[((size_t)n * DM + c0 + u) * SL + l];
            #pragma unroll
            for (int u = 0; u < 4; ++u) {
                hh[u] = bf16_rne(xv[u]);
                ll[u] = bf16_rne(xv[u] - bf16_to_f(hh[u]));
            }
            const int idx = ((lo >> 4) * 4 + (c0 >> 5)) * 512
                          + (((c0 >> 3) & 3) * 16 + (lo & 15)) * 8 + (c0 & 7);
            ushort4 hv; hv.x = hh[0]; hv.y = hh[1]; hv.z = hh[2]; hv.w = hh[3];
            ushort4 lv; lv.x = ll[0]; lv.y = ll[1]; lv.z = ll[2]; lv.w = ll[3];
            *(ushort4*)&Ah[idx] = hv;
            *(ushort4*)&Al[idx] = lv;
        }
    }
    __syncthreads();

    const int wave = tid >> 6;
    const int lane = tid & 63;
    const int dcol = lane & 15;
    const int dbase = wave * 32;

    f32x4 acc[3][2][4];
    #pragma unroll
    for (int dt = 0; dt < 2; ++dt) {
        const int d = dbase + dt * 16 + dcol;
        const float b0 = bq[d], b1 = bk[d], b2 = bv[d];
        #pragma unroll
        for (int lt = 0; lt < 4; ++lt) {
            acc[0][dt][lt] = (f32x4){b0, b0, b0, b0};
            acc[1][dt][lt] = (f32x4){b1, b1, b1, b1};
            acc[2][dt][lt] = (f32x4){b2, b2, b2, b2};
        }
    }

    const bf16x8* WhV = (const bf16x8*)Wh;
    const bf16x8* WlV = (const bf16x8*)Wl;
    #pragma unroll
    for (int ks = 0; ks < 4; ++ks) {
        bf16x8 bh[3][2], bl[3][2];
        #pragma unroll
        for (int m = 0; m < 3; ++m)
            #pragma unroll
            for (int dt = 0; dt < 2; ++dt) {
                const int fi = ((m * 8 + wave * 2 + dt) * 4 + ks) * 64 + lane;
                bh[m][dt] = WhV[fi];
                bl[m][dt] = WlV[fi];
            }
        #pragma unroll
        for (int lt = 0; lt < 4; ++lt) {
            const bf16x8 ah = *(const bf16x8*)&Ah[((lt * 4 + ks) * 64 + lane) * 8];
            const bf16x8 al = *(const bf16x8*)&Al[((lt * 4 + ks) * 64 + lane) * 8];
            #pragma unroll
            for (int m = 0; m < 3; ++m)
                #pragma unroll
                for (int dt = 0; dt < 2; ++dt) {
                    acc[m][dt][lt] = __builtin_amdgcn_mfma_f32_16x16x32_bf16(
                        ah, bh[m][dt], acc[m][dt][lt], 0, 0, 0);
                    acc[m][dt][lt] = __builtin_amdgcn_mfma_f32_16x16x32_bf16(
                        al, bh[m][dt], acc[m][dt][lt], 0, 0, 0);
                    acc[m][dt][lt] = __builtin_amdgcn_mfma_f32_16x16x32_bf16(
                        ah, bl[m][dt], acc[m][dt][lt], 0, 0, 0);
                }
        }
    }

    // Epilogue: sigmoid(q), exp(k), exp(k)*v + per-block column sums.
    const int lrow0 = (lane >> 4) * 4;
    float psk[2] = {0.f, 0.f}, pskv[2] = {0.f, 0.f};
    #pragma unroll
    for (int dt = 0; dt < 2; ++dt) {
        const int d = dbase + dt * 16 + dcol;
        #pragma unroll
        for (int lt = 0; lt < 4; ++lt) {
            const f32x4 q4 = acc[0][dt][lt];
            const f32x4 k4 = acc[1][dt][lt];
            const f32x4 v4 = acc[2][dt][lt];
            #pragma unroll
            for (int r = 0; r < 4; ++r) {
                const int l = l0 + lt * 16 + lrow0 + r;
                const size_t idx = ((size_t)n * SL + l) * DM + d;
                const float e = __expf(k4[r]);
                const float z = e * v4[r];
                sq[idx]  = 1.f / (1.f + __expf(-q4[r]));
                ek[idx]  = e;
                ekv[idx] = z;
                psk[dt]  += e;
                pskv[dt] += z;
            }
        }
    }
    #pragma unroll
    for (int dt = 0; dt < 2; ++dt) {
        float a = psk[dt], b = pskv[dt];
        a += __shfl_xor(a, 16, 64); a += __shfl_xor(a, 32, 64);
        b += __shfl_xor(b, 16, 64); b += __shfl_xor(b, 32, 64);
        if ((lane >> 4) == 0) {
            const size_t o = ((size_t)n * 32 + bx) * DM + dbase + dt * 16 + dcol;
            Pk [o] = a;
            Pkv[o] = b;
        }
    }
}

// Reduce the 32 per-block segments to full-L sums.
__global__ __launch_bounds__(128) void totals_final(
    const float* __restrict__ Pk, const float* __restrict__ Pkv,
    float* __restrict__ Sk, float* __restrict__ Skv)
{
    const int n = blockIdx.x;
    const int d = threadIdx.x;
    float sk = 0.f, skv = 0.f;
    #pragma unroll
    for (int seg = 0; seg < 32; ++seg) {
        sk  += Pk [(n * 32 + seg) * DM + d];
        skv += Pkv[(n * 32 + seg) * DM + d];
    }
    Sk [n * DM + d] = sk;
    Skv[n * DM + d] = skv;
}

// Band correction, strided-i: thread (il,dg) handles i = ibase+il+8k, k=0..7.
// All il groups stream the SAME j rows (offset <=7) -> one HBM fetch per block.
// Weights: 8 contiguous floats per (il,col) from T, broadcast across dg lanes.
__global__ __launch_bounds__(256, 4) void band_kernel(
    const float* __restrict__ ek, const float* __restrict__ ekv,
    const float* __restrict__ T,
    const float* __restrict__ Sk, const float* __restrict__ Skv,
    float* __restrict__ sqy)
{
    const int lid  = blockIdx.x;
    const int xcd  = lid & 7;
    const int slot = lid >> 3;
    const int n    = slot >> 2;
    const int sub  = slot & 3;
    const int bi   = xcd * 4 + sub;       // 0..31
    const int ibase = bi * 64;

    const int dg = threadIdx.x & 31;
    const int il = threadIdx.x >> 5;
    const int d4 = dg * 4;
    const int i0 = ibase + il;

    const float4 Sk4  = *(const float4*)(Sk  + n * DM + d4);
    const float4 Skv4 = *(const float4*)(Skv + n * DM + d4);
    float4 accd[8], accn[8];
    #pragma unroll
    for (int k = 0; k < 8; ++k) { accd[k] = Sk4; accn[k] = Skv4; }

    const int jlo = (i0 - 63 > 0) ? i0 - 63 : 0;
    const int jhi = (i0 + 119 < SL - 1) ? i0 + 119 : SL - 1;

    const float* wp = T + ((size_t)(bi * 8 + il) * 184 + (jlo - i0 + 63)) * 8;
    const float* pe = ek  + ((size_t)n * SL + jlo) * DM + d4;
    const float* pv = ekv + ((size_t)n * SL + jlo) * DM + d4;

    for (int j = jlo; j <= jhi; ++j) {
        const float4 e4  = *(const float4*)pe; pe += DM;
        const float4 kv4 = *(const float4*)pv; pv += DM;
        const float4 w0 = *(const float4*)wp;
        const float4 w1 = *(const float4*)(wp + 4); wp += 8;
        const float wk[8] = {w0.x, w0.y, w0.z, w0.w, w1.x, w1.y, w1.z, w1.w};
        #pragma unroll
        for (int k = 0; k < 8; ++k) {
            const float w = wk[k];
            accd[k].x += w * e4.x;  accd[k].y += w * e4.y;
            accd[k].z += w * e4.z;  accd[k].w += w * e4.w;
            accn[k].x += w * kv4.x; accn[k].y += w * kv4.y;
            accn[k].z += w * kv4.z; accn[k].w += w * kv4.w;
        }
    }

    #pragma unroll
    for (int k = 0; k < 8; ++k) {
        const int i = i0 + 8 * k;
        const size_t idx = ((size_t)n * SL + i) * DM + d4;
        const float4 s = *(const float4*)(sqy + idx);
        float4 yv;
        yv.x = s.x * accn[k].x / accd[k].x;
        yv.y = s.y * accn[k].y / accd[k].y;
        yv.z = s.z * accn[k].z / accd[k].z;
        yv.w = s.w * accn[k].w / accd[k].w;
        *(float4*)(sqy + idx) = yv;
    }
}

// Output projection: out[n,c,l] = sum_d y[n,l,d] * Wo[d,c] + bo[c]
__global__ __launch_bounds__(256) void out_kernel(
    const float* __restrict__ y, const float* __restrict__ Wo,
    const float* __restrict__ bo, float* __restrict__ out)
{
    __shared__ __align__(16) float ys[64][129];
    const int n  = blockIdx.y;
    const int l0 = blockIdx.x * 64;
    const int tid = threadIdx.x;

    #pragma unroll
    for (int w = 0; w < 32; ++w) {
        int idx = w * 256 + tid;
        int ll = idx >> 7, d = idx & 127;
        ys[ll][d] = y[((size_t)n * SL + l0 + ll) * DM + d];
    }
    __syncthreads();

    const int ll = tid & 63;
    const int cg = tid >> 6;
    for (int chunk = 0; chunk < 4; ++chunk) {
        const int c0 = cg * 32 + chunk * 8;
        float acc[8];
        #pragma unroll
        for (int j = 0; j < 8; ++j) acc[j] = bo[c0 + j];
        for (int dd = 0; dd < DM; ++dd) {
            float yv = ys[ll][dd];
            const float4* wr = (const float4*)(Wo + dd * DM + c0);
            float4 w0 = wr[0], w1 = wr[1];
            acc[0] += yv * w0.x; acc[1] += yv * w0.y;
            acc[2] += yv * w0.z; acc[3] += yv * w0.w;
            acc[4] += yv * w1.x; acc[5] += yv * w1.y;
            acc[6] += yv * w1.z; acc[7] += yv * w1.w;
        }
        #pragma unroll
        for (int j = 0; j < 8; ++j)
            out[((size_t)n * DM + c0 + j) * SL + l0 + ll] = acc[j];
    }
}

extern "C" void kernel_launch(void* const* d_in, const int* in_sizes, int n_in,
                              void* d_out, int out_size, void* d_ws, size_t ws_size,
                              hipStream_t stream)
{
    const float* x        = (const float*)d_in[0];
    const float* Wq       = (const float*)d_in[1];
    const float* bq       = (const float*)d_in[2];
    const float* Wk       = (const float*)d_in[3];
    const float* bk       = (const float*)d_in[4];
    const float* Wv       = (const float*)d_in[5];
    const float* bv       = (const float*)d_in[6];
    const float* Wo       = (const float*)d_in[7];
    const float* bo       = (const float*)d_in[8];
    const float* pos_bias = (const float*)d_in[9];
    float* out = (float*)d_out;

    float* ws  = (float*)d_ws;
    const size_t NLD = (size_t)NB * SL * DM;
    float* sq   = ws;
    float* ek   = sq   + NLD;
    float* ekv  = ek   + NLD;
    float* T    = ekv  + NLD;                      // 32*8*184*8 = 376832
    float* Sk   = T    + (size_t)32 * 8 * 184 * 8;
    float* Skv  = Sk   + (size_t)NB * DM;
    float* Pk   = Skv  + (size_t)NB * DM;
    float* Pkv  = Pk   + (size_t)NB * 32 * DM;
    ushort* Wh  = (ushort*)(Pkv + (size_t)NB * 32 * DM);
    ushort* Wl  = Wh + (size_t)3 * DM * DM;

    build_W     <<<dim3(96),       512, 0, stream>>>(Wq, Wk, Wv, Wh, Wl);
    build_T     <<<dim3(256),      256, 0, stream>>>(pos_bias, T);
    qkv_kernel  <<<dim3(32, NB),   256, 0, stream>>>(x, Wh, Wl, bq, bk, bv,
                                                     sq, ek, ekv, Pk, Pkv);
    totals_final<<<dim3(NB),       128, 0, stream>>>(Pk, Pkv, Sk, Skv);
    band_kernel <<<dim3(NB * 32),  256, 0, stream>>>(ek, ekv, T, Sk, Skv, sq);
    out_kernel  <<<dim3(32, NB),   256, 0, stream>>>(sq, Wo, bo, out);
}

// Round 4
// 282.667 us; speedup vs baseline: 2.3492x; 1.3658x over previous
//
#include <hip/hip_runtime.h>
#include <math.h>

#define NB 32
#define DM 128
#define SL 2048
#define WIN 64

typedef __attribute__((ext_vector_type(8))) short bf16x8;
typedef __attribute__((ext_vector_type(4))) float f32x4;

__device__ inline ushort bf16_rne(float f) {
    union { float f; unsigned u; } v; v.f = f;
    unsigned u = v.u;
    return (ushort)((u + 0x7FFFu + ((u >> 16) & 1u)) >> 16);
}
__device__ inline float bf16_to_f(ushort h) {
    union { unsigned u; float f; } v; v.u = ((unsigned)h) << 16;
    return v.f;
}

// ---------------------------------------------------------------------------
// ws layout (floats):
//   sq   : NB*SL*DM   sigmoid(q); overwritten in-place with y by band_kernel
//   ek   : NB*SL*DM   exp(k)
//   ekv  : NB*SL*DM   exp(k)*v
//   T    : 32*8*184*8 strided-band weight table  T[b][il][col][k]
//   Sk   : NB*DM      sum_l ek
//   Skv  : NB*DM      sum_l ekv
//   Pk   : NB*32*DM   per-qkv-block partial sums
//   Pkv  : NB*32*DM
//   Wh   : 4*128*128 bf16 (ushort) fragment-ordered hi parts (Wq,Wk,Wv,Wo)
//   Wl   : same, lo parts
// ---------------------------------------------------------------------------

// Pack Wq/Wk/Wv/Wo into MFMA B-fragment order, split hi/lo bf16.
// B frag: lane holds k = ks*32 + (lane>>4)*8 + j, col = ct*16 + (lane&15).
// For Wq/Wk/Wv: k=c (row), col=d.  For Wo: k=d (row), col=c. Same formula.
__global__ __launch_bounds__(512) void build_W(
    const float* __restrict__ Wq, const float* __restrict__ Wk,
    const float* __restrict__ Wv, const float* __restrict__ Wo,
    ushort* __restrict__ Wh, ushort* __restrict__ Wl)
{
    const int id = blockIdx.x;            // (mat*8+ct)*4+ks, 0..127
    const int mat = id >> 5;
    const int ct = (id & 31) >> 2, ks = id & 3;
    const int t = threadIdx.x;            // lane*8 + j
    const int lane = t >> 3, j = t & 7;
    const int k = ks * 32 + (lane >> 4) * 8 + j;
    const int col = ct * 16 + (lane & 15);
    const float* W = (mat == 0) ? Wq : ((mat == 1) ? Wk : ((mat == 2) ? Wv : Wo));
    float w = W[k * DM + col];
    ushort h = bf16_rne(w);
    Wh[(size_t)id * 512 + t] = h;
    Wl[(size_t)id * 512 + t] = bf16_rne(w - bf16_to_f(h));
}

// Strided-band weight table: for thread (b, il) handling i = b*64+il+8k,
// col = j - (b*64+il) + 63 in [0,184): T[...] = e^{pb[i][j]}-1 inside band else 0.
__global__ __launch_bounds__(256) void build_T(
    const float* __restrict__ pos_bias, float* __restrict__ T)
{
    const int b = blockIdx.x >> 3, il = blockIdx.x & 7;
    const int i0 = b * 64 + il;
    for (int t = threadIdx.x; t < 184 * 8; t += 256) {
        const int col = t >> 3, k = t & 7;
        const int i = i0 + 8 * k;
        const int j = i0 + col - 63;
        const int jj = col - 8 * k;               // = j - i + 63
        float val = 0.f;
        if (jj >= 0 && jj < 127 && j >= 0 && j < SL)
            val = __expf(pos_bias[(size_t)i * SL + j]) - 1.f;
        T[((size_t)(b * 8 + il) * 184 + col) * 8 + k] = val;
    }
}

// QKV projection via split-bf16 MFMA (16x16x32). Block = (n, 64 l's), 4 waves.
__global__ __launch_bounds__(256, 2) void qkv_kernel(
    const float* __restrict__ x,
    const ushort* __restrict__ Wh, const ushort* __restrict__ Wl,
    const float* __restrict__ bq, const float* __restrict__ bk,
    const float* __restrict__ bv,
    float* __restrict__ sq, float* __restrict__ ek, float* __restrict__ ekv,
    float* __restrict__ Pk, float* __restrict__ Pkv)
{
    __shared__ ushort Ah[64 * 128];   // frag order: ((lt*4+ks)*64+lane)*8+j
    __shared__ ushort Al[64 * 128];
    const int n = blockIdx.y, bx = blockIdx.x, l0 = bx * 64;
    const int tid = threadIdx.x;

    {
        const int lo = tid & 63;
        const int cq = tid >> 6;
        const int l  = l0 + lo;
        for (int cc = 0; cc < 8; ++cc) {
            const int c0 = cc * 16 + cq * 4;
            float xv[4]; ushort hh[4], ll[4];
            #pragma unroll
            for (int u = 0; u < 4; ++u)
                xv[u] = x[((size_t)n * DM + c0 + u) * SL + l];
            #pragma unroll
            for (int u = 0; u < 4; ++u) {
                hh[u] = bf16_rne(xv[u]);
                ll[u] = bf16_rne(xv[u] - bf16_to_f(hh[u]));
            }
            const int idx = ((lo >> 4) * 4 + (c0 >> 5)) * 512
                          + (((c0 >> 3) & 3) * 16 + (lo & 15)) * 8 + (c0 & 7);
            ushort4 hv; hv.x = hh[0]; hv.y = hh[1]; hv.z = hh[2]; hv.w = hh[3];
            ushort4 lv; lv.x = ll[0]; lv.y = ll[1]; lv.z = ll[2]; lv.w = ll[3];
            *(ushort4*)&Ah[idx] = hv;
            *(ushort4*)&Al[idx] = lv;
        }
    }
    __syncthreads();

    const int wave = tid >> 6;
    const int lane = tid & 63;
    const int dcol = lane & 15;
    const int dbase = wave * 32;

    f32x4 acc[3][2][4];
    #pragma unroll
    for (int dt = 0; dt < 2; ++dt) {
        const int d = dbase + dt * 16 + dcol;
        const float b0 = bq[d], b1 = bk[d], b2 = bv[d];
        #pragma unroll
        for (int lt = 0; lt < 4; ++lt) {
            acc[0][dt][lt] = (f32x4){b0, b0, b0, b0};
            acc[1][dt][lt] = (f32x4){b1, b1, b1, b1};
            acc[2][dt][lt] = (f32x4){b2, b2, b2, b2};
        }
    }

    const bf16x8* WhV = (const bf16x8*)Wh;
    const bf16x8* WlV = (const bf16x8*)Wl;
    #pragma unroll
    for (int ks = 0; ks < 4; ++ks) {
        bf16x8 bh[3][2], bl[3][2];
        #pragma unroll
        for (int m = 0; m < 3; ++m)
            #pragma unroll
            for (int dt = 0; dt < 2; ++dt) {
                const int fi = ((m * 8 + wave * 2 + dt) * 4 + ks) * 64 + lane;
                bh[m][dt] = WhV[fi];
                bl[m][dt] = WlV[fi];
            }
        #pragma unroll
        for (int lt = 0; lt < 4; ++lt) {
            const bf16x8 ah = *(const bf16x8*)&Ah[((lt * 4 + ks) * 64 + lane) * 8];
            const bf16x8 al = *(const bf16x8*)&Al[((lt * 4 + ks) * 64 + lane) * 8];
            #pragma unroll
            for (int m = 0; m < 3; ++m)
                #pragma unroll
                for (int dt = 0; dt < 2; ++dt) {
                    acc[m][dt][lt] = __builtin_amdgcn_mfma_f32_16x16x32_bf16(
                        ah, bh[m][dt], acc[m][dt][lt], 0, 0, 0);
                    acc[m][dt][lt] = __builtin_amdgcn_mfma_f32_16x16x32_bf16(
                        al, bh[m][dt], acc[m][dt][lt], 0, 0, 0);
                    acc[m][dt][lt] = __builtin_amdgcn_mfma_f32_16x16x32_bf16(
                        ah, bl[m][dt], acc[m][dt][lt], 0, 0, 0);
                }
        }
    }

    const int lrow0 = (lane >> 4) * 4;
    float psk[2] = {0.f, 0.f}, pskv[2] = {0.f, 0.f};
    #pragma unroll
    for (int dt = 0; dt < 2; ++dt) {
        const int d = dbase + dt * 16 + dcol;
        #pragma unroll
        for (int lt = 0; lt < 4; ++lt) {
            const f32x4 q4 = acc[0][dt][lt];
            const f32x4 k4 = acc[1][dt][lt];
            const f32x4 v4 = acc[2][dt][lt];
            #pragma unroll
            for (int r = 0; r < 4; ++r) {
                const int l = l0 + lt * 16 + lrow0 + r;
                const size_t idx = ((size_t)n * SL + l) * DM + d;
                const float e = __expf(k4[r]);
                const float z = e * v4[r];
                sq[idx]  = 1.f / (1.f + __expf(-q4[r]));
                ek[idx]  = e;
                ekv[idx] = z;
                psk[dt]  += e;
                pskv[dt] += z;
            }
        }
    }
    #pragma unroll
    for (int dt = 0; dt < 2; ++dt) {
        float a = psk[dt], b = pskv[dt];
        a += __shfl_xor(a, 16, 64); a += __shfl_xor(a, 32, 64);
        b += __shfl_xor(b, 16, 64); b += __shfl_xor(b, 32, 64);
        if ((lane >> 4) == 0) {
            const size_t o = ((size_t)n * 32 + bx) * DM + dbase + dt * 16 + dcol;
            Pk [o] = a;
            Pkv[o] = b;
        }
    }
}

// Reduce the 32 per-block segments to full-L sums.
__global__ __launch_bounds__(128) void totals_final(
    const float* __restrict__ Pk, const float* __restrict__ Pkv,
    float* __restrict__ Sk, float* __restrict__ Skv)
{
    const int n = blockIdx.x;
    const int d = threadIdx.x;
    float sk = 0.f, skv = 0.f;
    #pragma unroll
    for (int seg = 0; seg < 32; ++seg) {
        sk  += Pk [(n * 32 + seg) * DM + d];
        skv += Pkv[(n * 32 + seg) * DM + d];
    }
    Sk [n * DM + d] = sk;
    Skv[n * DM + d] = skv;
}

// Band correction, strided-i: thread (il,dg) handles i = ibase+il+8k, k=0..7.
__global__ __launch_bounds__(256, 4) void band_kernel(
    const float* __restrict__ ek, const float* __restrict__ ekv,
    const float* __restrict__ T,
    const float* __restrict__ Sk, const float* __restrict__ Skv,
    float* __restrict__ sqy)
{
    const int lid  = blockIdx.x;
    const int xcd  = lid & 7;
    const int slot = lid >> 3;
    const int n    = slot >> 2;
    const int sub  = slot & 3;
    const int bi   = xcd * 4 + sub;       // 0..31
    const int ibase = bi * 64;

    const int dg = threadIdx.x & 31;
    const int il = threadIdx.x >> 5;
    const int d4 = dg * 4;
    const int i0 = ibase + il;

    const float4 Sk4  = *(const float4*)(Sk  + n * DM + d4);
    const float4 Skv4 = *(const float4*)(Skv + n * DM + d4);
    float4 accd[8], accn[8];
    #pragma unroll
    for (int k = 0; k < 8; ++k) { accd[k] = Sk4; accn[k] = Skv4; }

    const int jlo = (i0 - 63 > 0) ? i0 - 63 : 0;
    const int jhi = (i0 + 119 < SL - 1) ? i0 + 119 : SL - 1;

    const float* wp = T + ((size_t)(bi * 8 + il) * 184 + (jlo - i0 + 63)) * 8;
    const float* pe = ek  + ((size_t)n * SL + jlo) * DM + d4;
    const float* pv = ekv + ((size_t)n * SL + jlo) * DM + d4;

    for (int j = jlo; j <= jhi; ++j) {
        const float4 e4  = *(const float4*)pe; pe += DM;
        const float4 kv4 = *(const float4*)pv; pv += DM;
        const float4 w0 = *(const float4*)wp;
        const float4 w1 = *(const float4*)(wp + 4); wp += 8;
        const float wk[8] = {w0.x, w0.y, w0.z, w0.w, w1.x, w1.y, w1.z, w1.w};
        #pragma unroll
        for (int k = 0; k < 8; ++k) {
            const float w = wk[k];
            accd[k].x += w * e4.x;  accd[k].y += w * e4.y;
            accd[k].z += w * e4.z;  accd[k].w += w * e4.w;
            accn[k].x += w * kv4.x; accn[k].y += w * kv4.y;
            accn[k].z += w * kv4.z; accn[k].w += w * kv4.w;
        }
    }

    #pragma unroll
    for (int k = 0; k < 8; ++k) {
        const int i = i0 + 8 * k;
        const size_t idx = ((size_t)n * SL + i) * DM + d4;
        const float4 s = *(const float4*)(sqy + idx);
        float4 yv;
        yv.x = s.x * accn[k].x / accd[k].x;
        yv.y = s.y * accn[k].y / accd[k].y;
        yv.z = s.z * accn[k].z / accd[k].z;
        yv.w = s.w * accn[k].w / accd[k].w;
        *(float4*)(sqy + idx) = yv;
    }
}

// Output projection via split-bf16 MFMA: out[n,c,l] = sum_d y[n,l,d]*Wo[d,c]+bo[c]
// Block = (n, 64 l's), 4 waves; wave w covers c in [w*32, w*32+32).
__global__ __launch_bounds__(256, 4) void out_kernel(
    const float* __restrict__ y,
    const ushort* __restrict__ Wh, const ushort* __restrict__ Wl,
    const float* __restrict__ bo, float* __restrict__ out)
{
    __shared__ union {
        struct { ushort Ah[64 * 128]; ushort Al[64 * 128]; } s;   // 32 KB
        float ot[128][65];                                        // 33.3 KB
    } u;
    const int n = blockIdx.y, l0 = blockIdx.x * 64;
    const int tid = threadIdx.x;

    // Stage y tile -> split bf16 in A-frag order. y is [n,l,d]: float4 loads.
    {
        const int lo = tid >> 2;          // 0..63
        const int cq = tid & 3;           // 0..3
        const float* yr = y + ((size_t)n * SL + l0 + lo) * DM;
        #pragma unroll
        for (int cc = 0; cc < 8; ++cc) {
            const int d0 = cc * 16 + cq * 4;
            const float4 yv4 = *(const float4*)(yr + d0);
            const float xv[4] = {yv4.x, yv4.y, yv4.z, yv4.w};
            ushort hh[4], ll[4];
            #pragma unroll
            for (int q = 0; q < 4; ++q) {
                hh[q] = bf16_rne(xv[q]);
                ll[q] = bf16_rne(xv[q] - bf16_to_f(hh[q]));
            }
            const int idx = ((lo >> 4) * 4 + (d0 >> 5)) * 512
                          + (((d0 >> 3) & 3) * 16 + (lo & 15)) * 8 + (d0 & 7);
            ushort4 hv; hv.x = hh[0]; hv.y = hh[1]; hv.z = hh[2]; hv.w = hh[3];
            ushort4 lv; lv.x = ll[0]; lv.y = ll[1]; lv.z = ll[2]; lv.w = ll[3];
            *(ushort4*)&u.s.Ah[idx] = hv;
            *(ushort4*)&u.s.Al[idx] = lv;
        }
    }
    __syncthreads();

    const int wave = tid >> 6;
    const int lane = tid & 63;
    const int ccol = lane & 15;
    const int cbase = wave * 32;

    f32x4 acc[2][4];
    #pragma unroll
    for (int ct = 0; ct < 2; ++ct) {
        const float b0 = bo[cbase + ct * 16 + ccol];
        #pragma unroll
        for (int lt = 0; lt < 4; ++lt)
            acc[ct][lt] = (f32x4){b0, b0, b0, b0};
    }

    const bf16x8* WhV = (const bf16x8*)Wh;
    const bf16x8* WlV = (const bf16x8*)Wl;
    #pragma unroll
    for (int ks = 0; ks < 4; ++ks) {
        bf16x8 bh[2], bl[2];
        #pragma unroll
        for (int ct = 0; ct < 2; ++ct) {
            const int fi = ((24 + wave * 2 + ct) * 4 + ks) * 64 + lane;  // mat=3
            bh[ct] = WhV[fi];
            bl[ct] = WlV[fi];
        }
        #pragma unroll
        for (int lt = 0; lt < 4; ++lt) {
            const bf16x8 ah = *(const bf16x8*)&u.s.Ah[((lt * 4 + ks) * 64 + lane) * 8];
            const bf16x8 al = *(const bf16x8*)&u.s.Al[((lt * 4 + ks) * 64 + lane) * 8];
            #pragma unroll
            for (int ct = 0; ct < 2; ++ct) {
                acc[ct][lt] = __builtin_amdgcn_mfma_f32_16x16x32_bf16(
                    ah, bh[ct], acc[ct][lt], 0, 0, 0);
                acc[ct][lt] = __builtin_amdgcn_mfma_f32_16x16x32_bf16(
                    al, bh[ct], acc[ct][lt], 0, 0, 0);
                acc[ct][lt] = __builtin_amdgcn_mfma_f32_16x16x32_bf16(
                    ah, bl[ct], acc[ct][lt], 0, 0, 0);
            }
        }
    }
    __syncthreads();   // all waves done reading frag LDS

    // Transpose through LDS: C frag row = l within tile, col = c.
    const int lrow0 = (lane >> 4) * 4;
    #pragma unroll
    for (int ct = 0; ct < 2; ++ct) {
        const int c = cbase + ct * 16 + ccol;
        #pragma unroll
        for (int lt = 0; lt < 4; ++lt) {
            #pragma unroll
            for (int r = 0; r < 4; ++r)
                u.ot[c][lt * 16 + lrow0 + r] = acc[ct][lt][r];
        }
    }
    __syncthreads();

    // Coalesced store: 64 contiguous floats per c row.
    #pragma unroll
    for (int rep = 0; rep < 32; ++rep) {
        const int e = rep * 256 + tid;
        const int c = e >> 6, l = e & 63;
        out[((size_t)n * DM + c) * SL + l0 + l] = u.ot[c][l];
    }
}

extern "C" void kernel_launch(void* const* d_in, const int* in_sizes, int n_in,
                              void* d_out, int out_size, void* d_ws, size_t ws_size,
                              hipStream_t stream)
{
    const float* x        = (const float*)d_in[0];
    const float* Wq       = (const float*)d_in[1];
    const float* bq       = (const float*)d_in[2];
    const float* Wk       = (const float*)d_in[3];
    const float* bk       = (const float*)d_in[4];
    const float* Wv       = (const float*)d_in[5];
    const float* bv       = (const float*)d_in[6];
    const float* Wo       = (const float*)d_in[7];
    const float* bo       = (const float*)d_in[8];
    const float* pos_bias = (const float*)d_in[9];
    float* out = (float*)d_out;

    float* ws  = (float*)d_ws;
    const size_t NLD = (size_t)NB * SL * DM;
    float* sq   = ws;
    float* ek   = sq   + NLD;
    float* ekv  = ek   + NLD;
    float* T    = ekv  + NLD;                      // 32*8*184*8 = 376832
    float* Sk   = T    + (size_t)32 * 8 * 184 * 8;
    float* Skv  = Sk   + (size_t)NB * DM;
    float* Pk   = Skv  + (size_t)NB * DM;
    float* Pkv  = Pk   + (size_t)NB * 32 * DM;
    ushort* Wh  = (ushort*)(Pkv + (size_t)NB * 32 * DM);
    ushort* Wl  = Wh + (size_t)4 * DM * DM;

    build_W     <<<dim3(128),      512, 0, stream>>>(Wq, Wk, Wv, Wo, Wh, Wl);
    build_T     <<<dim3(256),      256, 0, stream>>>(pos_bias, T);
    qkv_kernel  <<<dim3(32, NB),   256, 0, stream>>>(x, Wh, Wl, bq, bk, bv,
                                                     sq, ek, ekv, Pk, Pkv);
    totals_final<<<dim3(NB),       128, 0, stream>>>(Pk, Pkv, Sk, Skv);
    band_kernel <<<dim3(NB * 32),  256, 0, stream>>>(ek, ekv, T, Sk, Skv, sq);
    out_kernel  <<<dim3(32, NB),   256, 0, stream>>>(sq, Wh, Wl, bo, out);
}

// Round 5
// 216.150 us; speedup vs baseline: 3.0722x; 1.3077x over previous
//
#include <hip/hip_runtime.h>
#include <math.h>

#define NB 32
#define DM 128
#define SL 2048
#define WIN 64
#define SLP (SL + 160)   // padded row length (shorts) of transposed bf16 arrays

typedef __attribute__((ext_vector_type(8))) short bf16x8;
typedef __attribute__((ext_vector_type(4))) float f32x4;

__device__ inline ushort bf16_rne(float f) {
    union { float f; unsigned u; } v; v.f = f;
    unsigned u = v.u;
    return (ushort)((u + 0x7FFFu + ((u >> 16) & 1u)) >> 16);
}
__device__ inline float bf16_to_f(ushort h) {
    union { unsigned u; float f; } v; v.u = ((unsigned)h) << 16;
    return v.f;
}

// ---------------------------------------------------------------------------
// ws layout (floats):
//   sq    : NB*SL*DM        sigmoid(q); overwritten in-place with y by band
//   ekT   : NB*DM*SLP/2     bf16 exp(k), transposed [n][d][64+j], zero margins
//   ekvT  : NB*DM*SLP/2     bf16 exp(k)*v, same layout
//   WB    : 128*5*64*8/2    bf16 banded weights in A-frag order per i-tile
//   Sk    : NB*DM           sum_l ek      (fp32 exact)
//   Skv   : NB*DM           sum_l ekv
//   Pk    : NB*32*DM        per-qkv-block partial sums
//   Pkv   : NB*32*DM
//   Wh/Wl : 4*128*128 each  bf16 split W (Wq,Wk,Wv,Wo), B-frag order
// ---------------------------------------------------------------------------

// Pack Wq/Wk/Wv/Wo into MFMA B-fragment order, split hi/lo bf16.
__global__ __launch_bounds__(512) void build_W(
    const float* __restrict__ Wq, const float* __restrict__ Wk,
    const float* __restrict__ Wv, const float* __restrict__ Wo,
    ushort* __restrict__ Wh, ushort* __restrict__ Wl)
{
    const int id = blockIdx.x;            // (mat*8+ct)*4+ks, 0..127
    const int mat = id >> 5;
    const int ct = (id & 31) >> 2, ks = id & 3;
    const int t = threadIdx.x;            // lane*8 + j
    const int lane = t >> 3, j = t & 7;
    const int k = ks * 32 + (lane >> 4) * 8 + j;
    const int col = ct * 16 + (lane & 15);
    const float* W = (mat == 0) ? Wq : ((mat == 1) ? Wk : ((mat == 2) ? Wv : Wo));
    float w = W[k * DM + col];
    ushort h = bf16_rne(w);
    Wh[(size_t)id * 512 + t] = h;
    Wl[(size_t)id * 512 + t] = bf16_rne(w - bf16_to_f(h));
}

// Banded weights in A-frag order per i-tile: A[m=i-i0][k=j-(i0-64)],
// = e^{pb[i][j]}-1 inside band (|i-j|<64, j valid), else 0.  bf16.
__global__ __launch_bounds__(256) void build_WB(
    const float* __restrict__ pos_bias, ushort* __restrict__ WB)
{
    const int it = blockIdx.x;           // 0..127
    const int i0 = it * 16;
    for (int t = threadIdx.x; t < 5 * 64 * 8; t += 256) {
        const int ks = t >> 9;
        const int lane = (t >> 3) & 63;
        const int jj = t & 7;
        const int m = lane & 15;
        const int k = ks * 32 + ((lane >> 4) << 3) + jj;
        const int i = i0 + m;
        const int j = i0 - 64 + k;
        const int rel = k - 64 - m;      // j - i
        float val = 0.f;
        if (rel > -WIN && rel < WIN && j >= 0 && j < SL)
            val = __expf(pos_bias[(size_t)i * SL + j]) - 1.f;
        WB[(size_t)it * 2560 + t] = bf16_rne(val);
    }
}

// Zero the 64-front / 96-back margins of each transposed row.
__global__ __launch_bounds__(256) void zero_margins(
    ushort* __restrict__ ekT, ushort* __restrict__ ekvT)
{
    const int row = blockIdx.x;          // 0 .. NB*DM-1
    const int t = threadIdx.x;
    if (t < 160) {
        const size_t base = (size_t)row * SLP;
        const int off = (t < 64) ? t : (SL + t);
        ekT [base + off] = 0;
        ekvT[base + off] = 0;
    }
}

// QKV projection via split-bf16 MFMA. Block = (n, 64 l's), 4 waves.
// Epilogue writes sq (fp32) + transposed bf16 ekT/ekvT + fp32 partial sums.
__global__ __launch_bounds__(256, 2) void qkv_kernel(
    const float* __restrict__ x,
    const ushort* __restrict__ Wh, const ushort* __restrict__ Wl,
    const float* __restrict__ bq, const float* __restrict__ bk,
    const float* __restrict__ bv,
    float* __restrict__ sq, ushort* __restrict__ ekT, ushort* __restrict__ ekvT,
    float* __restrict__ Pk, float* __restrict__ Pkv)
{
    __shared__ ushort Ah[64 * 128];   // frag order: ((lt*4+ks)*64+lane)*8+j
    __shared__ ushort Al[64 * 128];
    const int n = blockIdx.y, bx = blockIdx.x, l0 = bx * 64;
    const int tid = threadIdx.x;

    {
        const int lo = tid & 63;
        const int cq = tid >> 6;
        const int l  = l0 + lo;
        for (int cc = 0; cc < 8; ++cc) {
            const int c0 = cc * 16 + cq * 4;
            float xv[4]; ushort hh[4], ll[4];
            #pragma unroll
            for (int u = 0; u < 4; ++u)
                xv[u] = x[((size_t)n * DM + c0 + u) * SL + l];
            #pragma unroll
            for (int u = 0; u < 4; ++u) {
                hh[u] = bf16_rne(xv[u]);
                ll[u] = bf16_rne(xv[u] - bf16_to_f(hh[u]));
            }
            const int idx = ((lo >> 4) * 4 + (c0 >> 5)) * 512
                          + (((c0 >> 3) & 3) * 16 + (lo & 15)) * 8 + (c0 & 7);
            ushort4 hv; hv.x = hh[0]; hv.y = hh[1]; hv.z = hh[2]; hv.w = hh[3];
            ushort4 lv; lv.x = ll[0]; lv.y = ll[1]; lv.z = ll[2]; lv.w = ll[3];
            *(ushort4*)&Ah[idx] = hv;
            *(ushort4*)&Al[idx] = lv;
        }
    }
    __syncthreads();

    const int wave = tid >> 6;
    const int lane = tid & 63;
    const int dcol = lane & 15;
    const int dbase = wave * 32;

    f32x4 acc[3][2][4];
    #pragma unroll
    for (int dt = 0; dt < 2; ++dt) {
        const int d = dbase + dt * 16 + dcol;
        const float b0 = bq[d], b1 = bk[d], b2 = bv[d];
        #pragma unroll
        for (int lt = 0; lt < 4; ++lt) {
            acc[0][dt][lt] = (f32x4){b0, b0, b0, b0};
            acc[1][dt][lt] = (f32x4){b1, b1, b1, b1};
            acc[2][dt][lt] = (f32x4){b2, b2, b2, b2};
        }
    }

    const bf16x8* WhV = (const bf16x8*)Wh;
    const bf16x8* WlV = (const bf16x8*)Wl;
    #pragma unroll
    for (int ks = 0; ks < 4; ++ks) {
        bf16x8 bh[3][2], bl[3][2];
        #pragma unroll
        for (int m = 0; m < 3; ++m)
            #pragma unroll
            for (int dt = 0; dt < 2; ++dt) {
                const int fi = ((m * 8 + wave * 2 + dt) * 4 + ks) * 64 + lane;
                bh[m][dt] = WhV[fi];
                bl[m][dt] = WlV[fi];
            }
        #pragma unroll
        for (int lt = 0; lt < 4; ++lt) {
            const bf16x8 ah = *(const bf16x8*)&Ah[((lt * 4 + ks) * 64 + lane) * 8];
            const bf16x8 al = *(const bf16x8*)&Al[((lt * 4 + ks) * 64 + lane) * 8];
            #pragma unroll
            for (int m = 0; m < 3; ++m)
                #pragma unroll
                for (int dt = 0; dt < 2; ++dt) {
                    acc[m][dt][lt] = __builtin_amdgcn_mfma_f32_16x16x32_bf16(
                        ah, bh[m][dt], acc[m][dt][lt], 0, 0, 0);
                    acc[m][dt][lt] = __builtin_amdgcn_mfma_f32_16x16x32_bf16(
                        al, bh[m][dt], acc[m][dt][lt], 0, 0, 0);
                    acc[m][dt][lt] = __builtin_amdgcn_mfma_f32_16x16x32_bf16(
                        ah, bl[m][dt], acc[m][dt][lt], 0, 0, 0);
                }
        }
    }

    const int lrow0 = (lane >> 4) * 4;
    float psk[2] = {0.f, 0.f}, pskv[2] = {0.f, 0.f};
    #pragma unroll
    for (int dt = 0; dt < 2; ++dt) {
        const int d = dbase + dt * 16 + dcol;
        const size_t tb = ((size_t)n * DM + d) * SLP + 64;
        #pragma unroll
        for (int lt = 0; lt < 4; ++lt) {
            const f32x4 q4 = acc[0][dt][lt];
            const f32x4 k4 = acc[1][dt][lt];
            const f32x4 v4 = acc[2][dt][lt];
            ushort eh[4], zh[4];
            #pragma unroll
            for (int r = 0; r < 4; ++r) {
                const int l = l0 + lt * 16 + lrow0 + r;
                const float e = __expf(k4[r]);
                const float z = e * v4[r];
                sq[((size_t)n * SL + l) * DM + d] = 1.f / (1.f + __expf(-q4[r]));
                eh[r] = bf16_rne(e);
                zh[r] = bf16_rne(z);
                psk[dt]  += e;
                pskv[dt] += z;
            }
            const int lrow = l0 + lt * 16 + lrow0;
            ushort4 ev; ev.x = eh[0]; ev.y = eh[1]; ev.z = eh[2]; ev.w = eh[3];
            ushort4 zv; zv.x = zh[0]; zv.y = zh[1]; zv.z = zh[2]; zv.w = zh[3];
            *(ushort4*)&ekT [tb + lrow] = ev;
            *(ushort4*)&ekvT[tb + lrow] = zv;
        }
    }
    #pragma unroll
    for (int dt = 0; dt < 2; ++dt) {
        float a = psk[dt], b = pskv[dt];
        a += __shfl_xor(a, 16, 64); a += __shfl_xor(a, 32, 64);
        b += __shfl_xor(b, 16, 64); b += __shfl_xor(b, 32, 64);
        if ((lane >> 4) == 0) {
            const size_t o = ((size_t)n * 32 + bx) * DM + dbase + dt * 16 + dcol;
            Pk [o] = a;
            Pkv[o] = b;
        }
    }
}

// Reduce the 32 per-block segments to full-L sums.
__global__ __launch_bounds__(128) void totals_final(
    const float* __restrict__ Pk, const float* __restrict__ Pkv,
    float* __restrict__ Sk, float* __restrict__ Skv)
{
    const int n = blockIdx.x;
    const int d = threadIdx.x;
    float sk = 0.f, skv = 0.f;
    #pragma unroll
    for (int seg = 0; seg < 32; ++seg) {
        sk  += Pk [(n * 32 + seg) * DM + d];
        skv += Pkv[(n * 32 + seg) * DM + d];
    }
    Sk [n * DM + d] = sk;
    Skv[n * DM + d] = skv;
}

// Band correction via MFMA. One wave per (n, 16-i tile): 5 K-steps of 32 j's,
// 8 d-tiles, num+den accumulated in C-frags initialized from Skv/Sk.
// y = sigmoid(q) * num / den written in-place over sq.
__global__ __launch_bounds__(256, 4) void band_kernel(
    const ushort* __restrict__ ekT, const ushort* __restrict__ ekvT,
    const ushort* __restrict__ WB,
    const float* __restrict__ Sk, const float* __restrict__ Skv,
    float* __restrict__ sqy)
{
    const int bid = blockIdx.x;          // 0..1023
    const int xcd = bid & 7;
    const int slot = bid >> 3;           // 0..127
    const int nsub = slot >> 5;          // 0..3
    const int itg  = slot & 31;          // 0..31
    const int n = xcd * 4 + nsub;        // 4 n's per XCD -> ~4.5 MB L2 set
    const int wave = threadIdx.x >> 6;
    const int lane = threadIdx.x & 63;
    const int it = itg * 4 + wave;       // 0..127
    const int i0 = it * 16;

    const int dcol = lane & 15;
    const int jgrp8 = (lane >> 4) << 3;

    f32x4 den[8], num[8];
    #pragma unroll
    for (int dt = 0; dt < 8; ++dt) {
        const float sk = Sk [n * DM + dt * 16 + dcol];
        const float sv = Skv[n * DM + dt * 16 + dcol];
        den[dt] = (f32x4){sk, sk, sk, sk};
        num[dt] = (f32x4){sv, sv, sv, sv};
    }

    const bf16x8* WBv = (const bf16x8*)(WB + (size_t)it * 2560);
    #pragma unroll
    for (int ks = 0; ks < 5; ++ks) {
        const bf16x8 a = WBv[ks * 64 + lane];
        const size_t jb = (size_t)i0 + ks * 32 + jgrp8;  // = 64 + (i0-64+ks*32+jgrp8)
        #pragma unroll
        for (int dt = 0; dt < 8; ++dt) {
            const int d = dt * 16 + dcol;
            const size_t rbase = ((size_t)n * DM + d) * SLP + jb;
            const bf16x8 bden = *(const bf16x8*)(ekT  + rbase);
            const bf16x8 bnum = *(const bf16x8*)(ekvT + rbase);
            den[dt] = __builtin_amdgcn_mfma_f32_16x16x32_bf16(a, bden, den[dt], 0, 0, 0);
            num[dt] = __builtin_amdgcn_mfma_f32_16x16x32_bf16(a, bnum, num[dt], 0, 0, 0);
        }
    }

    const int irow0 = (lane >> 4) << 2;
    #pragma unroll
    for (int dt = 0; dt < 8; ++dt) {
        const int d = dt * 16 + dcol;
        #pragma unroll
        for (int r = 0; r < 4; ++r) {
            const int i = i0 + irow0 + r;
            const size_t idx = ((size_t)n * SL + i) * DM + d;
            const float s = sqy[idx];
            sqy[idx] = s * num[dt][r] / den[dt][r];
        }
    }
}

// Output projection via split-bf16 MFMA: out[n,c,l] = sum_d y[n,l,d]*Wo[d,c]+bo[c]
__global__ __launch_bounds__(256, 4) void out_kernel(
    const float* __restrict__ y,
    const ushort* __restrict__ Wh, const ushort* __restrict__ Wl,
    const float* __restrict__ bo, float* __restrict__ out)
{
    __shared__ union {
        struct { ushort Ah[64 * 128]; ushort Al[64 * 128]; } s;   // 32 KB
        float ot[128][65];                                        // 33.3 KB
    } u;
    const int n = blockIdx.y, l0 = blockIdx.x * 64;
    const int tid = threadIdx.x;

    {
        const int lo = tid >> 2;
        const int cq = tid & 3;
        const float* yr = y + ((size_t)n * SL + l0 + lo) * DM;
        #pragma unroll
        for (int cc = 0; cc < 8; ++cc) {
            const int d0 = cc * 16 + cq * 4;
            const float4 yv4 = *(const float4*)(yr + d0);
            const float xv[4] = {yv4.x, yv4.y, yv4.z, yv4.w};
            ushort hh[4], ll[4];
            #pragma unroll
            for (int q = 0; q < 4; ++q) {
                hh[q] = bf16_rne(xv[q]);
                ll[q] = bf16_rne(xv[q] - bf16_to_f(hh[q]));
            }
            const int idx = ((lo >> 4) * 4 + (d0 >> 5)) * 512
                          + (((d0 >> 3) & 3) * 16 + (lo & 15)) * 8 + (d0 & 7);
            ushort4 hv; hv.x = hh[0]; hv.y = hh[1]; hv.z = hh[2]; hv.w = hh[3];
            ushort4 lv; lv.x = ll[0]; lv.y = ll[1]; lv.z = ll[2]; lv.w = ll[3];
            *(ushort4*)&u.s.Ah[idx] = hv;
            *(ushort4*)&u.s.Al[idx] = lv;
        }
    }
    __syncthreads();

    const int wave = tid >> 6;
    const int lane = tid & 63;
    const int ccol = lane & 15;
    const int cbase = wave * 32;

    f32x4 acc[2][4];
    #pragma unroll
    for (int ct = 0; ct < 2; ++ct) {
        const float b0 = bo[cbase + ct * 16 + ccol];
        #pragma unroll
        for (int lt = 0; lt < 4; ++lt)
            acc[ct][lt] = (f32x4){b0, b0, b0, b0};
    }

    const bf16x8* WhV = (const bf16x8*)Wh;
    const bf16x8* WlV = (const bf16x8*)Wl;
    #pragma unroll
    for (int ks = 0; ks < 4; ++ks) {
        bf16x8 bh[2], bl[2];
        #pragma unroll
        for (int ct = 0; ct < 2; ++ct) {
            const int fi = ((24 + wave * 2 + ct) * 4 + ks) * 64 + lane;  // mat=3
            bh[ct] = WhV[fi];
            bl[ct] = WlV[fi];
        }
        #pragma unroll
        for (int lt = 0; lt < 4; ++lt) {
            const bf16x8 ah = *(const bf16x8*)&u.s.Ah[((lt * 4 + ks) * 64 + lane) * 8];
            const bf16x8 al = *(const bf16x8*)&u.s.Al[((lt * 4 + ks) * 64 + lane) * 8];
            #pragma unroll
            for (int ct = 0; ct < 2; ++ct) {
                acc[ct][lt] = __builtin_amdgcn_mfma_f32_16x16x32_bf16(
                    ah, bh[ct], acc[ct][lt], 0, 0, 0);
                acc[ct][lt] = __builtin_amdgcn_mfma_f32_16x16x32_bf16(
                    al, bh[ct], acc[ct][lt], 0, 0, 0);
                acc[ct][lt] = __builtin_amdgcn_mfma_f32_16x16x32_bf16(
                    ah, bl[ct], acc[ct][lt], 0, 0, 0);
            }
        }
    }
    __syncthreads();

    const int lrow0 = (lane >> 4) * 4;
    #pragma unroll
    for (int ct = 0; ct < 2; ++ct) {
        const int c = cbase + ct * 16 + ccol;
        #pragma unroll
        for (int lt = 0; lt < 4; ++lt) {
            #pragma unroll
            for (int r = 0; r < 4; ++r)
                u.ot[c][lt * 16 + lrow0 + r] = acc[ct][lt][r];
        }
    }
    __syncthreads();

    #pragma unroll
    for (int rep = 0; rep < 32; ++rep) {
        const int e = rep * 256 + tid;
        const int c = e >> 6, l = e & 63;
        out[((size_t)n * DM + c) * SL + l0 + l] = u.ot[c][l];
    }
}

extern "C" void kernel_launch(void* const* d_in, const int* in_sizes, int n_in,
                              void* d_out, int out_size, void* d_ws, size_t ws_size,
                              hipStream_t stream)
{
    const float* x        = (const float*)d_in[0];
    const float* Wq       = (const float*)d_in[1];
    const float* bq       = (const float*)d_in[2];
    const float* Wk       = (const float*)d_in[3];
    const float* bk       = (const float*)d_in[4];
    const float* Wv       = (const float*)d_in[5];
    const float* bv       = (const float*)d_in[6];
    const float* Wo       = (const float*)d_in[7];
    const float* bo       = (const float*)d_in[8];
    const float* pos_bias = (const float*)d_in[9];
    float* out = (float*)d_out;

    float* ws  = (float*)d_ws;
    const size_t NLD = (size_t)NB * SL * DM;
    float*  sq   = ws;
    ushort* ekT  = (ushort*)(sq + NLD);
    ushort* ekvT = ekT  + (size_t)NB * DM * SLP;
    ushort* WB   = ekvT + (size_t)NB * DM * SLP;
    float*  Sk   = (float*)(WB + (size_t)128 * 2560);
    float*  Skv  = Sk   + (size_t)NB * DM;
    float*  Pk   = Skv  + (size_t)NB * DM;
    float*  Pkv  = Pk   + (size_t)NB * 32 * DM;
    ushort* Wh   = (ushort*)(Pkv + (size_t)NB * 32 * DM);
    ushort* Wl   = Wh + (size_t)4 * DM * DM;

    build_W     <<<dim3(128),      512, 0, stream>>>(Wq, Wk, Wv, Wo, Wh, Wl);
    build_WB    <<<dim3(128),      256, 0, stream>>>(pos_bias, WB);
    zero_margins<<<dim3(NB * DM),  256, 0, stream>>>(ekT, ekvT);
    qkv_kernel  <<<dim3(32, NB),   256, 0, stream>>>(x, Wh, Wl, bq, bk, bv,
                                                     sq, ekT, ekvT, Pk, Pkv);
    totals_final<<<dim3(NB),       128, 0, stream>>>(Pk, Pkv, Sk, Skv);
    band_kernel <<<dim3(NB * 32),  256, 0, stream>>>(ekT, ekvT, WB, Sk, Skv, sq);
    out_kernel  <<<dim3(32, NB),   256, 0, stream>>>(sq, Wh, Wl, bo, out);
}

// Round 6
// 193.631 us; speedup vs baseline: 3.4295x; 1.1163x over previous
//
#include <hip/hip_runtime.h>
#include <math.h>

#define NB 32
#define DM 128
#define SL 2048
#define WIN 64
#define SLP (SL + 160)   // padded row length (shorts) of transposed bf16 arrays

typedef __attribute__((ext_vector_type(8))) short bf16x8;
typedef __attribute__((ext_vector_type(4))) float f32x4;

__device__ inline ushort bf16_rne(float f) {
    union { float f; unsigned u; } v; v.f = f;
    unsigned u = v.u;
    return (ushort)((u + 0x7FFFu + ((u >> 16) & 1u)) >> 16);
}
__device__ inline float bf16_to_f(ushort h) {
    union { unsigned u; float f; } v; v.u = ((unsigned)h) << 16;
    return v.f;
}

// ---------------------------------------------------------------------------
// ws layout (floats):
//   sq    : NB*SL*DM        sigmoid(q)  (read-only after qkv)
//   ekT   : NB*DM*SLP/2     bf16 exp(k), transposed [n][d][64+j], zero margins
//   ekvT  : NB*DM*SLP/2     bf16 exp(k)*v, same layout
//   WB    : 128*5*64*8/2    bf16 banded weights in A-frag order per i-tile
//   Sk    : NB*DM           sum_l ek      (fp32 exact)
//   Skv   : NB*DM           sum_l ekv
//   Pk    : NB*32*DM        per-qkv-block partial sums
//   Pkv   : NB*32*DM
//   Wh/Wl : 4*128*128 each  bf16 split W (Wq,Wk,Wv,Wo), B-frag order
// ---------------------------------------------------------------------------

// Pack Wq/Wk/Wv/Wo into MFMA B-fragment order, split hi/lo bf16.
__global__ __launch_bounds__(512) void build_W(
    const float* __restrict__ Wq, const float* __restrict__ Wk,
    const float* __restrict__ Wv, const float* __restrict__ Wo,
    ushort* __restrict__ Wh, ushort* __restrict__ Wl)
{
    const int id = blockIdx.x;            // (mat*8+ct)*4+ks, 0..127
    const int mat = id >> 5;
    const int ct = (id & 31) >> 2, ks = id & 3;
    const int t = threadIdx.x;            // lane*8 + j
    const int lane = t >> 3, j = t & 7;
    const int k = ks * 32 + (lane >> 4) * 8 + j;
    const int col = ct * 16 + (lane & 15);
    const float* W = (mat == 0) ? Wq : ((mat == 1) ? Wk : ((mat == 2) ? Wv : Wo));
    float w = W[k * DM + col];
    ushort h = bf16_rne(w);
    Wh[(size_t)id * 512 + t] = h;
    Wl[(size_t)id * 512 + t] = bf16_rne(w - bf16_to_f(h));
}

// Banded weights in A-frag order per i-tile: A[m=i-i0][k=j-(i0-64)],
// = e^{pb[i][j]}-1 inside band (|i-j|<64, j valid), else 0.  bf16.
__global__ __launch_bounds__(256) void build_WB(
    const float* __restrict__ pos_bias, ushort* __restrict__ WB)
{
    const int it = blockIdx.x;           // 0..127
    const int i0 = it * 16;
    for (int t = threadIdx.x; t < 5 * 64 * 8; t += 256) {
        const int ks = t >> 9;
        const int lane = (t >> 3) & 63;
        const int jj = t & 7;
        const int m = lane & 15;
        const int k = ks * 32 + ((lane >> 4) << 3) + jj;
        const int i = i0 + m;
        const int j = i0 - 64 + k;
        const int rel = k - 64 - m;      // j - i
        float val = 0.f;
        if (rel > -WIN && rel < WIN && j >= 0 && j < SL)
            val = __expf(pos_bias[(size_t)i * SL + j]) - 1.f;
        WB[(size_t)it * 2560 + t] = bf16_rne(val);
    }
}

// Zero the 64-front / 96-back margins of each transposed row.
__global__ __launch_bounds__(256) void zero_margins(
    ushort* __restrict__ ekT, ushort* __restrict__ ekvT)
{
    const int row = blockIdx.x;          // 0 .. NB*DM-1
    const int t = threadIdx.x;
    if (t < 160) {
        const size_t base = (size_t)row * SLP;
        const int off = (t < 64) ? t : (SL + t);
        ekT [base + off] = 0;
        ekvT[base + off] = 0;
    }
}

// QKV projection via split-bf16 MFMA. Block = (n, 64 l's), 4 waves.
// Epilogue writes sq (fp32) + transposed bf16 ekT/ekvT + fp32 partial sums.
__global__ __launch_bounds__(256, 2) void qkv_kernel(
    const float* __restrict__ x,
    const ushort* __restrict__ Wh, const ushort* __restrict__ Wl,
    const float* __restrict__ bq, const float* __restrict__ bk,
    const float* __restrict__ bv,
    float* __restrict__ sq, ushort* __restrict__ ekT, ushort* __restrict__ ekvT,
    float* __restrict__ Pk, float* __restrict__ Pkv)
{
    __shared__ ushort Ah[64 * 128];   // frag order: ((lt*4+ks)*64+lane)*8+j
    __shared__ ushort Al[64 * 128];
    const int n = blockIdx.y, bx = blockIdx.x, l0 = bx * 64;
    const int tid = threadIdx.x;

    {
        const int lo = tid & 63;
        const int cq = tid >> 6;
        const int l  = l0 + lo;
        for (int cc = 0; cc < 8; ++cc) {
            const int c0 = cc * 16 + cq * 4;
            float xv[4]; ushort hh[4], ll[4];
            #pragma unroll
            for (int u = 0; u < 4; ++u)
                xv[u] = x[((size_t)n * DM + c0 + u) * SL + l];
            #pragma unroll
            for (int u = 0; u < 4; ++u) {
                hh[u] = bf16_rne(xv[u]);
                ll[u] = bf16_rne(xv[u] - bf16_to_f(hh[u]));
            }
            const int idx = ((lo >> 4) * 4 + (c0 >> 5)) * 512
                          + (((c0 >> 3) & 3) * 16 + (lo & 15)) * 8 + (c0 & 7);
            ushort4 hv; hv.x = hh[0]; hv.y = hh[1]; hv.z = hh[2]; hv.w = hh[3];
            ushort4 lv; lv.x = ll[0]; lv.y = ll[1]; lv.z = ll[2]; lv.w = ll[3];
            *(ushort4*)&Ah[idx] = hv;
            *(ushort4*)&Al[idx] = lv;
        }
    }
    __syncthreads();

    const int wave = tid >> 6;
    const int lane = tid & 63;
    const int dcol = lane & 15;
    const int dbase = wave * 32;

    f32x4 acc[3][2][4];
    #pragma unroll
    for (int dt = 0; dt < 2; ++dt) {
        const int d = dbase + dt * 16 + dcol;
        const float b0 = bq[d], b1 = bk[d], b2 = bv[d];
        #pragma unroll
        for (int lt = 0; lt < 4; ++lt) {
            acc[0][dt][lt] = (f32x4){b0, b0, b0, b0};
            acc[1][dt][lt] = (f32x4){b1, b1, b1, b1};
            acc[2][dt][lt] = (f32x4){b2, b2, b2, b2};
        }
    }

    const bf16x8* WhV = (const bf16x8*)Wh;
    const bf16x8* WlV = (const bf16x8*)Wl;
    #pragma unroll
    for (int ks = 0; ks < 4; ++ks) {
        bf16x8 bh[3][2], bl[3][2];
        #pragma unroll
        for (int m = 0; m < 3; ++m)
            #pragma unroll
            for (int dt = 0; dt < 2; ++dt) {
                const int fi = ((m * 8 + wave * 2 + dt) * 4 + ks) * 64 + lane;
                bh[m][dt] = WhV[fi];
                bl[m][dt] = WlV[fi];
            }
        #pragma unroll
        for (int lt = 0; lt < 4; ++lt) {
            const bf16x8 ah = *(const bf16x8*)&Ah[((lt * 4 + ks) * 64 + lane) * 8];
            const bf16x8 al = *(const bf16x8*)&Al[((lt * 4 + ks) * 64 + lane) * 8];
            #pragma unroll
            for (int m = 0; m < 3; ++m)
                #pragma unroll
                for (int dt = 0; dt < 2; ++dt) {
                    acc[m][dt][lt] = __builtin_amdgcn_mfma_f32_16x16x32_bf16(
                        ah, bh[m][dt], acc[m][dt][lt], 0, 0, 0);
                    acc[m][dt][lt] = __builtin_amdgcn_mfma_f32_16x16x32_bf16(
                        al, bh[m][dt], acc[m][dt][lt], 0, 0, 0);
                    acc[m][dt][lt] = __builtin_amdgcn_mfma_f32_16x16x32_bf16(
                        ah, bl[m][dt], acc[m][dt][lt], 0, 0, 0);
                }
        }
    }

    const int lrow0 = (lane >> 4) * 4;
    float psk[2] = {0.f, 0.f}, pskv[2] = {0.f, 0.f};
    #pragma unroll
    for (int dt = 0; dt < 2; ++dt) {
        const int d = dbase + dt * 16 + dcol;
        const size_t tb = ((size_t)n * DM + d) * SLP + 64;
        #pragma unroll
        for (int lt = 0; lt < 4; ++lt) {
            const f32x4 q4 = acc[0][dt][lt];
            const f32x4 k4 = acc[1][dt][lt];
            const f32x4 v4 = acc[2][dt][lt];
            ushort eh[4], zh[4];
            #pragma unroll
            for (int r = 0; r < 4; ++r) {
                const int l = l0 + lt * 16 + lrow0 + r;
                const float e = __expf(k4[r]);
                const float z = e * v4[r];
                sq[((size_t)n * SL + l) * DM + d] = 1.f / (1.f + __expf(-q4[r]));
                eh[r] = bf16_rne(e);
                zh[r] = bf16_rne(z);
                psk[dt]  += e;
                pskv[dt] += z;
            }
            const int lrow = l0 + lt * 16 + lrow0;
            ushort4 ev; ev.x = eh[0]; ev.y = eh[1]; ev.z = eh[2]; ev.w = eh[3];
            ushort4 zv; zv.x = zh[0]; zv.y = zh[1]; zv.z = zh[2]; zv.w = zh[3];
            *(ushort4*)&ekT [tb + lrow] = ev;
            *(ushort4*)&ekvT[tb + lrow] = zv;
        }
    }
    #pragma unroll
    for (int dt = 0; dt < 2; ++dt) {
        float a = psk[dt], b = pskv[dt];
        a += __shfl_xor(a, 16, 64); a += __shfl_xor(a, 32, 64);
        b += __shfl_xor(b, 16, 64); b += __shfl_xor(b, 32, 64);
        if ((lane >> 4) == 0) {
            const size_t o = ((size_t)n * 32 + bx) * DM + dbase + dt * 16 + dcol;
            Pk [o] = a;
            Pkv[o] = b;
        }
    }
}

// Reduce the 32 per-block segments to full-L sums.
__global__ __launch_bounds__(128) void totals_final(
    const float* __restrict__ Pk, const float* __restrict__ Pkv,
    float* __restrict__ Sk, float* __restrict__ Skv)
{
    const int n = blockIdx.x;
    const int d = threadIdx.x;
    float sk = 0.f, skv = 0.f;
    #pragma unroll
    for (int seg = 0; seg < 32; ++seg) {
        sk  += Pk [(n * 32 + seg) * DM + d];
        skv += Pkv[(n * 32 + seg) * DM + d];
    }
    Sk [n * DM + d] = sk;
    Skv[n * DM + d] = skv;
}

// FUSED band correction + output projection.
// Block = (n, 64-i tile), 4 waves; wave w handles i-tile it = itg*4+w.
// Phase 1 (per wave): banded MFMA -> num/den C-frags, gate with sigmoid(q),
//   scatter y into LDS as split-bf16 A-frags (y never touches HBM).
// Phase 2 (block): out = y @ Wo + bo via split-bf16 MFMA, LDS transpose,
//   coalesced [n,c,l] store.
__global__ __launch_bounds__(256, 4) void band_out_kernel(
    const ushort* __restrict__ ekT, const ushort* __restrict__ ekvT,
    const ushort* __restrict__ WB,
    const float* __restrict__ Sk, const float* __restrict__ Skv,
    const float* __restrict__ sqg,
    const ushort* __restrict__ Wh, const ushort* __restrict__ Wl,
    const float* __restrict__ bo, float* __restrict__ out)
{
    __shared__ union {
        struct { ushort Ah[64 * 128]; ushort Al[64 * 128]; } s;   // 32 KB
        float ot[128][65];                                        // 33.3 KB
    } u;

    const int bid = blockIdx.x;          // 0..1023
    const int xcd = bid & 7;
    const int slot = bid >> 3;           // 0..127
    const int nsub = slot >> 5;          // 0..3
    const int itg  = slot & 31;          // 0..31  (fast-varying: same-n blocks adjacent)
    const int n = xcd * 4 + nsub;        // 4 n's per XCD
    const int wave = threadIdx.x >> 6;
    const int lane = threadIdx.x & 63;
    const int it = itg * 4 + wave;       // 0..127
    const int i0 = it * 16;
    const int l0 = itg * 64;             // block's row base (= i range)

    const int dcol = lane & 15;
    const int jgrp8 = (lane >> 4) << 3;

    // ---- Phase 1: banded MFMA ----
    f32x4 den[8], num[8];
    #pragma unroll
    for (int dt = 0; dt < 8; ++dt) {
        const float sk = Sk [n * DM + dt * 16 + dcol];
        const float sv = Skv[n * DM + dt * 16 + dcol];
        den[dt] = (f32x4){sk, sk, sk, sk};
        num[dt] = (f32x4){sv, sv, sv, sv};
    }

    const bf16x8* WBv = (const bf16x8*)(WB + (size_t)it * 2560);
    #pragma unroll
    for (int ks = 0; ks < 5; ++ks) {
        const bf16x8 a = WBv[ks * 64 + lane];
        const size_t jb = (size_t)i0 + ks * 32 + jgrp8;  // = 64 + (i0-64+ks*32+jgrp8)
        #pragma unroll
        for (int dt = 0; dt < 8; ++dt) {
            const int d = dt * 16 + dcol;
            const size_t rbase = ((size_t)n * DM + d) * SLP + jb;
            const bf16x8 bden = *(const bf16x8*)(ekT  + rbase);
            const bf16x8 bnum = *(const bf16x8*)(ekvT + rbase);
            den[dt] = __builtin_amdgcn_mfma_f32_16x16x32_bf16(a, bden, den[dt], 0, 0, 0);
            num[dt] = __builtin_amdgcn_mfma_f32_16x16x32_bf16(a, bnum, num[dt], 0, 0, 0);
        }
    }

    // Gate with sigmoid(q); scatter y into LDS as split-bf16 A-frags.
    // A-frag index for (row lo in [0,64), col d): same formula as qkv staging.
    const int irow0 = (lane >> 4) << 2;
    #pragma unroll
    for (int dt = 0; dt < 8; ++dt) {
        const int d = dt * 16 + dcol;
        #pragma unroll
        for (int r = 0; r < 4; ++r) {
            const int i = i0 + irow0 + r;
            const float s = sqg[((size_t)n * SL + i) * DM + d];
            const float y = s * num[dt][r] / den[dt][r];
            const int lo = wave * 16 + irow0 + r;
            const int idx = ((lo >> 4) * 4 + (d >> 5)) * 512
                          + (((d >> 3) & 3) * 16 + (lo & 15)) * 8 + (d & 7);
            const ushort h = bf16_rne(y);
            u.s.Ah[idx] = h;
            u.s.Al[idx] = bf16_rne(y - bf16_to_f(h));
        }
    }
    __syncthreads();

    // ---- Phase 2: out projection (identical structure to old out_kernel) ----
    const int ccol = lane & 15;
    const int cbase = wave * 32;

    f32x4 acc[2][4];
    #pragma unroll
    for (int ct = 0; ct < 2; ++ct) {
        const float b0 = bo[cbase + ct * 16 + ccol];
        #pragma unroll
        for (int lt = 0; lt < 4; ++lt)
            acc[ct][lt] = (f32x4){b0, b0, b0, b0};
    }

    const bf16x8* WhV = (const bf16x8*)Wh;
    const bf16x8* WlV = (const bf16x8*)Wl;
    #pragma unroll
    for (int ks = 0; ks < 4; ++ks) {
        bf16x8 bh[2], bl[2];
        #pragma unroll
        for (int ct = 0; ct < 2; ++ct) {
            const int fi = ((24 + wave * 2 + ct) * 4 + ks) * 64 + lane;  // mat=3 (Wo)
            bh[ct] = WhV[fi];
            bl[ct] = WlV[fi];
        }
        #pragma unroll
        for (int lt = 0; lt < 4; ++lt) {
            const bf16x8 ah = *(const bf16x8*)&u.s.Ah[((lt * 4 + ks) * 64 + lane) * 8];
            const bf16x8 al = *(const bf16x8*)&u.s.Al[((lt * 4 + ks) * 64 + lane) * 8];
            #pragma unroll
            for (int ct = 0; ct < 2; ++ct) {
                acc[ct][lt] = __builtin_amdgcn_mfma_f32_16x16x32_bf16(
                    ah, bh[ct], acc[ct][lt], 0, 0, 0);
                acc[ct][lt] = __builtin_amdgcn_mfma_f32_16x16x32_bf16(
                    al, bh[ct], acc[ct][lt], 0, 0, 0);
                acc[ct][lt] = __builtin_amdgcn_mfma_f32_16x16x32_bf16(
                    ah, bl[ct], acc[ct][lt], 0, 0, 0);
            }
        }
    }
    __syncthreads();   // all waves done reading frag LDS

    // Transpose through LDS: C frag row = l within tile, col = c.
    const int lrow0 = (lane >> 4) * 4;
    #pragma unroll
    for (int ct = 0; ct < 2; ++ct) {
        const int c = cbase + ct * 16 + ccol;
        #pragma unroll
        for (int lt = 0; lt < 4; ++lt) {
            #pragma unroll
            for (int r = 0; r < 4; ++r)
                u.ot[c][lt * 16 + lrow0 + r] = acc[ct][lt][r];
        }
    }
    __syncthreads();

    // Coalesced store: 64 contiguous floats per c row.
    const int tid = threadIdx.x;
    #pragma unroll
    for (int rep = 0; rep < 32; ++rep) {
        const int e = rep * 256 + tid;
        const int c = e >> 6, l = e & 63;
        out[((size_t)n * DM + c) * SL + l0 + l] = u.ot[c][l];
    }
}

extern "C" void kernel_launch(void* const* d_in, const int* in_sizes, int n_in,
                              void* d_out, int out_size, void* d_ws, size_t ws_size,
                              hipStream_t stream)
{
    const float* x        = (const float*)d_in[0];
    const float* Wq       = (const float*)d_in[1];
    const float* bq       = (const float*)d_in[2];
    const float* Wk       = (const float*)d_in[3];
    const float* bk       = (const float*)d_in[4];
    const float* Wv       = (const float*)d_in[5];
    const float* bv       = (const float*)d_in[6];
    const float* Wo       = (const float*)d_in[7];
    const float* bo       = (const float*)d_in[8];
    const float* pos_bias = (const float*)d_in[9];
    float* out = (float*)d_out;

    float* ws  = (float*)d_ws;
    const size_t NLD = (size_t)NB * SL * DM;
    float*  sq   = ws;
    ushort* ekT  = (ushort*)(sq + NLD);
    ushort* ekvT = ekT  + (size_t)NB * DM * SLP;
    ushort* WB   = ekvT + (size_t)NB * DM * SLP;
    float*  Sk   = (float*)(WB + (size_t)128 * 2560);
    float*  Skv  = Sk   + (size_t)NB * DM;
    float*  Pk   = Skv  + (size_t)NB * DM;
    float*  Pkv  = Pk   + (size_t)NB * 32 * DM;
    ushort* Wh   = (ushort*)(Pkv + (size_t)NB * 32 * DM);
    ushort* Wl   = Wh + (size_t)4 * DM * DM;

    build_W       <<<dim3(128),      512, 0, stream>>>(Wq, Wk, Wv, Wo, Wh, Wl);
    build_WB      <<<dim3(128),      256, 0, stream>>>(pos_bias, WB);
    zero_margins  <<<dim3(NB * DM),  256, 0, stream>>>(ekT, ekvT);
    qkv_kernel    <<<dim3(32, NB),   256, 0, stream>>>(x, Wh, Wl, bq, bk, bv,
                                                       sq, ekT, ekvT, Pk, Pkv);
    totals_final  <<<dim3(NB),       128, 0, stream>>>(Pk, Pkv, Sk, Skv);
    band_out_kernel<<<dim3(NB * 32), 256, 0, stream>>>(ekT, ekvT, WB, Sk, Skv, sq,
                                                       Wh, Wl, bo, out);
}

// Round 7
// 193.251 us; speedup vs baseline: 3.4362x; 1.0020x over previous
//
#include <hip/hip_runtime.h>
#include <math.h>

#define NB 32
#define DM 128
#define SL 2048
#define WIN 64
#define SLP (SL + 160)   // padded row length (shorts) of transposed bf16 arrays
#define YST 132          // ylds row stride (floats): 132*4=528 B, 16-B aligned, %32 banks = 4

typedef __attribute__((ext_vector_type(8))) short bf16x8;
typedef __attribute__((ext_vector_type(4))) float f32x4;

__device__ inline ushort bf16_rne(float f) {
    union { float f; unsigned u; } v; v.f = f;
    unsigned u = v.u;
    return (ushort)((u + 0x7FFFu + ((u >> 16) & 1u)) >> 16);
}
__device__ inline float bf16_to_f(ushort h) {
    union { unsigned u; float f; } v; v.u = ((unsigned)h) << 16;
    return v.f;
}

// ---------------------------------------------------------------------------
// ws layout (floats):
//   sq    : NB*SL*DM        sigmoid(q)  (read-only after qkv)
//   ekT   : NB*DM*SLP/2     bf16 exp(k), transposed [n][d][64+j], zero margins
//   ekvT  : NB*DM*SLP/2     bf16 exp(k)*v, same layout
//   WB    : 128*5*64*8/2    bf16 banded weights in A-frag order per i-tile
//   Sk    : NB*DM           sum_l ek      (fp32 exact)
//   Skv   : NB*DM           sum_l ekv
//   Pk    : NB*32*DM        per-qkv-block partial sums
//   Pkv   : NB*32*DM
//   Wh/Wl : 4*128*128 each  bf16 split W (Wq,Wk,Wv,Wo), B-frag order
// ---------------------------------------------------------------------------

// Pack Wq/Wk/Wv/Wo into MFMA B-fragment order, split hi/lo bf16.
__global__ __launch_bounds__(512) void build_W(
    const float* __restrict__ Wq, const float* __restrict__ Wk,
    const float* __restrict__ Wv, const float* __restrict__ Wo,
    ushort* __restrict__ Wh, ushort* __restrict__ Wl)
{
    const int id = blockIdx.x;            // (mat*8+ct)*4+ks, 0..127
    const int mat = id >> 5;
    const int ct = (id & 31) >> 2, ks = id & 3;
    const int t = threadIdx.x;            // lane*8 + j
    const int lane = t >> 3, j = t & 7;
    const int k = ks * 32 + (lane >> 4) * 8 + j;
    const int col = ct * 16 + (lane & 15);
    const float* W = (mat == 0) ? Wq : ((mat == 1) ? Wk : ((mat == 2) ? Wv : Wo));
    float w = W[k * DM + col];
    ushort h = bf16_rne(w);
    Wh[(size_t)id * 512 + t] = h;
    Wl[(size_t)id * 512 + t] = bf16_rne(w - bf16_to_f(h));
}

// Banded weights in A-frag order per i-tile: A[m=i-i0][k=j-(i0-64)],
// = e^{pb[i][j]}-1 inside band (|i-j|<64, j valid), else 0.  bf16.
__global__ __launch_bounds__(256) void build_WB(
    const float* __restrict__ pos_bias, ushort* __restrict__ WB)
{
    const int it = blockIdx.x;           // 0..127
    const int i0 = it * 16;
    for (int t = threadIdx.x; t < 5 * 64 * 8; t += 256) {
        const int ks = t >> 9;
        const int lane = (t >> 3) & 63;
        const int jj = t & 7;
        const int m = lane & 15;
        const int k = ks * 32 + ((lane >> 4) << 3) + jj;
        const int i = i0 + m;
        const int j = i0 - 64 + k;
        const int rel = k - 64 - m;      // j - i
        float val = 0.f;
        if (rel > -WIN && rel < WIN && j >= 0 && j < SL)
            val = __expf(pos_bias[(size_t)i * SL + j]) - 1.f;
        WB[(size_t)it * 2560 + t] = bf16_rne(val);
    }
}

// Zero the 64-front / 96-back margins of each transposed row.
__global__ __launch_bounds__(256) void zero_margins(
    ushort* __restrict__ ekT, ushort* __restrict__ ekvT)
{
    const int row = blockIdx.x;          // 0 .. NB*DM-1
    const int t = threadIdx.x;
    if (t < 160) {
        const size_t base = (size_t)row * SLP;
        const int off = (t < 64) ? t : (SL + t);
        ekT [base + off] = 0;
        ekvT[base + off] = 0;
    }
}

// QKV projection via split-bf16 MFMA. Block = (n, 64 l's), 4 waves.
// Epilogue writes sq (fp32) + transposed bf16 ekT/ekvT + fp32 partial sums.
__global__ __launch_bounds__(256, 2) void qkv_kernel(
    const float* __restrict__ x,
    const ushort* __restrict__ Wh, const ushort* __restrict__ Wl,
    const float* __restrict__ bq, const float* __restrict__ bk,
    const float* __restrict__ bv,
    float* __restrict__ sq, ushort* __restrict__ ekT, ushort* __restrict__ ekvT,
    float* __restrict__ Pk, float* __restrict__ Pkv)
{
    __shared__ ushort Ah[64 * 128];   // frag order: ((lt*4+ks)*64+lane)*8+j
    __shared__ ushort Al[64 * 128];
    const int n = blockIdx.y, bx = blockIdx.x, l0 = bx * 64;
    const int tid = threadIdx.x;

    {
        const int lo = tid & 63;
        const int cq = tid >> 6;
        const int l  = l0 + lo;
        for (int cc = 0; cc < 8; ++cc) {
            const int c0 = cc * 16 + cq * 4;
            float xv[4]; ushort hh[4], ll[4];
            #pragma unroll
            for (int u = 0; u < 4; ++u)
                xv[u] = x[((size_t)n * DM + c0 + u) * SL + l];
            #pragma unroll
            for (int u = 0; u < 4; ++u) {
                hh[u] = bf16_rne(xv[u]);
                ll[u] = bf16_rne(xv[u] - bf16_to_f(hh[u]));
            }
            const int idx = ((lo >> 4) * 4 + (c0 >> 5)) * 512
                          + (((c0 >> 3) & 3) * 16 + (lo & 15)) * 8 + (c0 & 7);
            ushort4 hv; hv.x = hh[0]; hv.y = hh[1]; hv.z = hh[2]; hv.w = hh[3];
            ushort4 lv; lv.x = ll[0]; lv.y = ll[1]; lv.z = ll[2]; lv.w = ll[3];
            *(ushort4*)&Ah[idx] = hv;
            *(ushort4*)&Al[idx] = lv;
        }
    }
    __syncthreads();

    const int wave = tid >> 6;
    const int lane = tid & 63;
    const int dcol = lane & 15;
    const int dbase = wave * 32;

    f32x4 acc[3][2][4];
    #pragma unroll
    for (int dt = 0; dt < 2; ++dt) {
        const int d = dbase + dt * 16 + dcol;
        const float b0 = bq[d], b1 = bk[d], b2 = bv[d];
        #pragma unroll
        for (int lt = 0; lt < 4; ++lt) {
            acc[0][dt][lt] = (f32x4){b0, b0, b0, b0};
            acc[1][dt][lt] = (f32x4){b1, b1, b1, b1};
            acc[2][dt][lt] = (f32x4){b2, b2, b2, b2};
        }
    }

    const bf16x8* WhV = (const bf16x8*)Wh;
    const bf16x8* WlV = (const bf16x8*)Wl;
    #pragma unroll
    for (int ks = 0; ks < 4; ++ks) {
        bf16x8 bh[3][2], bl[3][2];
        #pragma unroll
        for (int m = 0; m < 3; ++m)
            #pragma unroll
            for (int dt = 0; dt < 2; ++dt) {
                const int fi = ((m * 8 + wave * 2 + dt) * 4 + ks) * 64 + lane;
                bh[m][dt] = WhV[fi];
                bl[m][dt] = WlV[fi];
            }
        #pragma unroll
        for (int lt = 0; lt < 4; ++lt) {
            const bf16x8 ah = *(const bf16x8*)&Ah[((lt * 4 + ks) * 64 + lane) * 8];
            const bf16x8 al = *(const bf16x8*)&Al[((lt * 4 + ks) * 64 + lane) * 8];
            #pragma unroll
            for (int m = 0; m < 3; ++m)
                #pragma unroll
                for (int dt = 0; dt < 2; ++dt) {
                    acc[m][dt][lt] = __builtin_amdgcn_mfma_f32_16x16x32_bf16(
                        ah, bh[m][dt], acc[m][dt][lt], 0, 0, 0);
                    acc[m][dt][lt] = __builtin_amdgcn_mfma_f32_16x16x32_bf16(
                        al, bh[m][dt], acc[m][dt][lt], 0, 0, 0);
                    acc[m][dt][lt] = __builtin_amdgcn_mfma_f32_16x16x32_bf16(
                        ah, bl[m][dt], acc[m][dt][lt], 0, 0, 0);
                }
        }
    }

    const int lrow0 = (lane >> 4) * 4;
    float psk[2] = {0.f, 0.f}, pskv[2] = {0.f, 0.f};
    #pragma unroll
    for (int dt = 0; dt < 2; ++dt) {
        const int d = dbase + dt * 16 + dcol;
        const size_t tb = ((size_t)n * DM + d) * SLP + 64;
        #pragma unroll
        for (int lt = 0; lt < 4; ++lt) {
            const f32x4 q4 = acc[0][dt][lt];
            const f32x4 k4 = acc[1][dt][lt];
            const f32x4 v4 = acc[2][dt][lt];
            ushort eh[4], zh[4];
            #pragma unroll
            for (int r = 0; r < 4; ++r) {
                const int l = l0 + lt * 16 + lrow0 + r;
                const float e = __expf(k4[r]);
                const float z = e * v4[r];
                sq[((size_t)n * SL + l) * DM + d] = 1.f / (1.f + __expf(-q4[r]));
                eh[r] = bf16_rne(e);
                zh[r] = bf16_rne(z);
                psk[dt]  += e;
                pskv[dt] += z;
            }
            const int lrow = l0 + lt * 16 + lrow0;
            ushort4 ev; ev.x = eh[0]; ev.y = eh[1]; ev.z = eh[2]; ev.w = eh[3];
            ushort4 zv; zv.x = zh[0]; zv.y = zh[1]; zv.z = zh[2]; zv.w = zh[3];
            *(ushort4*)&ekT [tb + lrow] = ev;
            *(ushort4*)&ekvT[tb + lrow] = zv;
        }
    }
    #pragma unroll
    for (int dt = 0; dt < 2; ++dt) {
        float a = psk[dt], b = pskv[dt];
        a += __shfl_xor(a, 16, 64); a += __shfl_xor(a, 32, 64);
        b += __shfl_xor(b, 16, 64); b += __shfl_xor(b, 32, 64);
        if ((lane >> 4) == 0) {
            const size_t o = ((size_t)n * 32 + bx) * DM + dbase + dt * 16 + dcol;
            Pk [o] = a;
            Pkv[o] = b;
        }
    }
}

// Reduce the 32 per-block segments to full-L sums.
__global__ __launch_bounds__(128) void totals_final(
    const float* __restrict__ Pk, const float* __restrict__ Pkv,
    float* __restrict__ Sk, float* __restrict__ Skv)
{
    const int n = blockIdx.x;
    const int d = threadIdx.x;
    float sk = 0.f, skv = 0.f;
    #pragma unroll
    for (int seg = 0; seg < 32; ++seg) {
        sk  += Pk [(n * 32 + seg) * DM + d];
        skv += Pkv[(n * 32 + seg) * DM + d];
    }
    Sk [n * DM + d] = sk;
    Skv[n * DM + d] = skv;
}

// FUSED band correction + output projection, wave-local handoff.
// Block = (n, 64-i tile), 4 waves; wave w owns i-tile it = itg*4+w (16 rows).
// Phase 1 (per wave): banded MFMA -> num/den, gate with sigmoid(q), write y
//   fp32 to this wave's OWN 16-row LDS stripe (conflict-free 4 B writes).
// Handoff (per wave): read own stripe back in A-octet order (float4, aligned),
//   convert to split-bf16 in registers. No cross-wave data flow.
// Phase 2 (per wave): out rows = own 16 i's, ALL 128 c: 8 c-tiles x 4 ks.
// Single barrier guards the ylds->ot LDS reuse; second guards ot->store.
__global__ __launch_bounds__(256, 4) void band_out_kernel(
    const ushort* __restrict__ ekT, const ushort* __restrict__ ekvT,
    const ushort* __restrict__ WB,
    const float* __restrict__ Sk, const float* __restrict__ Skv,
    const float* __restrict__ sqg,
    const ushort* __restrict__ Wh, const ushort* __restrict__ Wl,
    const float* __restrict__ bo, float* __restrict__ out)
{
    __shared__ __align__(16) union {
        float ylds[64 * YST];   // 33.8 KB  y fp32, [row l_local][col d]
        float ot[128 * 65];     // 33.3 KB  out transpose buffer [c][l_local]
    } u;

    const int bid = blockIdx.x;          // 0..1023
    const int xcd = bid & 7;
    const int slot = bid >> 3;           // 0..127
    const int nsub = slot >> 5;          // 0..3
    const int itg  = slot & 31;          // 0..31  (fast-varying: same-n blocks adjacent)
    const int n = xcd * 4 + nsub;        // 4 n's per XCD
    const int wave = threadIdx.x >> 6;
    const int lane = threadIdx.x & 63;
    const int it = itg * 4 + wave;       // 0..127
    const int i0 = it * 16;
    const int l0 = itg * 64;             // block's row base (= i range)

    const int dcol = lane & 15;
    const int jgrp8 = (lane >> 4) << 3;

    // ---- Phase 1: banded MFMA ----
    f32x4 den[8], num[8];
    #pragma unroll
    for (int dt = 0; dt < 8; ++dt) {
        const float sk = Sk [n * DM + dt * 16 + dcol];
        const float sv = Skv[n * DM + dt * 16 + dcol];
        den[dt] = (f32x4){sk, sk, sk, sk};
        num[dt] = (f32x4){sv, sv, sv, sv};
    }

    const bf16x8* WBv = (const bf16x8*)(WB + (size_t)it * 2560);
    #pragma unroll
    for (int ks = 0; ks < 5; ++ks) {
        const bf16x8 a = WBv[ks * 64 + lane];
        const size_t jb = (size_t)i0 + ks * 32 + jgrp8;  // = 64 + (i0-64+ks*32+jgrp8)
        #pragma unroll
        for (int dt = 0; dt < 8; ++dt) {
            const int d = dt * 16 + dcol;
            const size_t rbase = ((size_t)n * DM + d) * SLP + jb;
            const bf16x8 bden = *(const bf16x8*)(ekT  + rbase);
            const bf16x8 bnum = *(const bf16x8*)(ekvT + rbase);
            den[dt] = __builtin_amdgcn_mfma_f32_16x16x32_bf16(a, bden, den[dt], 0, 0, 0);
            num[dt] = __builtin_amdgcn_mfma_f32_16x16x32_bf16(a, bnum, num[dt], 0, 0, 0);
        }
    }

    // Gate with sigmoid(q); write fp32 y into this wave's own LDS stripe.
    const int irow0 = (lane >> 4) << 2;
    #pragma unroll
    for (int dt = 0; dt < 8; ++dt) {
        const int d = dt * 16 + dcol;
        #pragma unroll
        for (int r = 0; r < 4; ++r) {
            const int i = i0 + irow0 + r;
            const float s = sqg[((size_t)n * SL + i) * DM + d];
            const float y = s * num[dt][r] / den[dt][r];
            u.ylds[(wave * 16 + irow0 + r) * YST + d] = y;
        }
    }

    // ---- Handoff: read own stripe in A-octet order (wave-coherent, no sync) --
    float af[4][8];
    {
        const int arow = wave * 16 + (lane & 15);
        #pragma unroll
        for (int ks = 0; ks < 4; ++ks) {
            const int base = arow * YST + ks * 32 + jgrp8;
            const float4 a0 = *(const float4*)&u.ylds[base];
            const float4 a1 = *(const float4*)&u.ylds[base + 4];
            af[ks][0] = a0.x; af[ks][1] = a0.y; af[ks][2] = a0.z; af[ks][3] = a0.w;
            af[ks][4] = a1.x; af[ks][5] = a1.y; af[ks][6] = a1.z; af[ks][7] = a1.w;
        }
    }
    __syncthreads();   // all waves done with ylds; ot may now overwrite

    bf16x8 yh[4], yl[4];
    #pragma unroll
    for (int ks = 0; ks < 4; ++ks) {
        #pragma unroll
        for (int t = 0; t < 8; ++t) {
            const float v = af[ks][t];
            const ushort h = bf16_rne(v);
            yh[ks][t] = (short)h;
            yl[ks][t] = (short)bf16_rne(v - bf16_to_f(h));
        }
    }

    // ---- Phase 2: out projection, own 16 rows x all 128 c ----
    f32x4 acc[8];
    #pragma unroll
    for (int ct = 0; ct < 8; ++ct) {
        const float b0 = bo[ct * 16 + dcol];
        acc[ct] = (f32x4){b0, b0, b0, b0};
    }

    const bf16x8* WhV = (const bf16x8*)Wh;
    const bf16x8* WlV = (const bf16x8*)Wl;
    #pragma unroll
    for (int ks = 0; ks < 4; ++ks) {
        #pragma unroll
        for (int ct = 0; ct < 8; ++ct) {
            const int fi = ((24 + ct) * 4 + ks) * 64 + lane;  // mat=3 (Wo)
            const bf16x8 bh = WhV[fi];
            const bf16x8 bl = WlV[fi];
            acc[ct] = __builtin_amdgcn_mfma_f32_16x16x32_bf16(yh[ks], bh, acc[ct], 0, 0, 0);
            acc[ct] = __builtin_amdgcn_mfma_f32_16x16x32_bf16(yl[ks], bh, acc[ct], 0, 0, 0);
            acc[ct] = __builtin_amdgcn_mfma_f32_16x16x32_bf16(yh[ks], bl, acc[ct], 0, 0, 0);
        }
    }

    // Transpose through LDS: ot[c][l_local]; C rows = wave's 16 l's.
    #pragma unroll
    for (int ct = 0; ct < 8; ++ct) {
        const int c = ct * 16 + dcol;
        #pragma unroll
        for (int r = 0; r < 4; ++r)
            u.ot[c * 65 + wave * 16 + irow0 + r] = acc[ct][r];
    }
    __syncthreads();

    // Coalesced store: 64 contiguous floats per c row.
    const int tid = threadIdx.x;
    #pragma unroll
    for (int rep = 0; rep < 32; ++rep) {
        const int e = rep * 256 + tid;
        const int c = e >> 6, l = e & 63;
        out[((size_t)n * DM + c) * SL + l0 + l] = u.ot[c * 65 + l];
    }
}

extern "C" void kernel_launch(void* const* d_in, const int* in_sizes, int n_in,
                              void* d_out, int out_size, void* d_ws, size_t ws_size,
                              hipStream_t stream)
{
    const float* x        = (const float*)d_in[0];
    const float* Wq       = (const float*)d_in[1];
    const float* bq       = (const float*)d_in[2];
    const float* Wk       = (const float*)d_in[3];
    const float* bk       = (const float*)d_in[4];
    const float* Wv       = (const float*)d_in[5];
    const float* bv       = (const float*)d_in[6];
    const float* Wo       = (const float*)d_in[7];
    const float* bo       = (const float*)d_in[8];
    const float* pos_bias = (const float*)d_in[9];
    float* out = (float*)d_out;

    float* ws  = (float*)d_ws;
    const size_t NLD = (size_t)NB * SL * DM;
    float*  sq   = ws;
    ushort* ekT  = (ushort*)(sq + NLD);
    ushort* ekvT = ekT  + (size_t)NB * DM * SLP;
    ushort* WB   = ekvT + (size_t)NB * DM * SLP;
    float*  Sk   = (float*)(WB + (size_t)128 * 2560);
    float*  Skv  = Sk   + (size_t)NB * DM;
    float*  Pk   = Skv  + (size_t)NB * DM;
    float*  Pkv  = Pk   + (size_t)NB * 32 * DM;
    ushort* Wh   = (ushort*)(Pkv + (size_t)NB * 32 * DM);
    ushort* Wl   = Wh + (size_t)4 * DM * DM;

    build_W       <<<dim3(128),      512, 0, stream>>>(Wq, Wk, Wv, Wo, Wh, Wl);
    build_WB      <<<dim3(128),      256, 0, stream>>>(pos_bias, WB);
    zero_margins  <<<dim3(NB * DM),  256, 0, stream>>>(ekT, ekvT);
    qkv_kernel    <<<dim3(32, NB),   256, 0, stream>>>(x, Wh, Wl, bq, bk, bv,
                                                       sq, ekT, ekvT, Pk, Pkv);
    totals_final  <<<dim3(NB),       128, 0, stream>>>(Pk, Pkv, Sk, Skv);
    band_out_kernel<<<dim3(NB * 32), 256, 0, stream>>>(ekT, ekvT, WB, Sk, Skv, sq,
                                                       Wh, Wl, bo, out);
}

// Round 8
// 173.981 us; speedup vs baseline: 3.8168x; 1.1108x over previous
//
#include <hip/hip_runtime.h>
#include <math.h>

#define NB 32
#define DM 128
#define SL 2048
#define WIN 64
#define NT  (SL / 16)    // 128 j-tiles of 16
#define PADF 4           // front pad tiles (j in [-64,0))
#define PADB 6           // back pad tiles  (j in [SL, SL+96))
#define NTP (NT + PADF + PADB)   // 138 tiles per (n)
#define YST 132          // ylds row stride (floats)

typedef __attribute__((ext_vector_type(8))) short bf16x8;
typedef __attribute__((ext_vector_type(4))) float f32x4;

__device__ inline ushort bf16_rne(float f) {
    union { float f; unsigned u; } v; v.f = f;
    unsigned u = v.u;
    return (ushort)((u + 0x7FFFu + ((u >> 16) & 1u)) >> 16);
}
__device__ inline float bf16_to_f(ushort h) {
    union { unsigned u; float f; } v; v.u = ((unsigned)h) << 16;
    return v.f;
}

// ---------------------------------------------------------------------------
// ws layout:
//   sq    : NB*SL*DM fp32     sigmoid(q)
//   ekTF  : NB*NTP*2048 bf16  exp(k) in 16-j x 128-d tiles [n][jt][d][jo],
//                             jt offset by PADF; pad tiles zeroed by setup
//   ekvTF : same              exp(k)*v
//   WB    : 128*2560 bf16     banded weights, A-frag order per 16-i tile
//   Sk/Skv: NB*DM fp32        full-L sums
//   Pk/Pkv: NB*32*DM fp32     per-block partials
//   Wh/Wl : 4*128*128 bf16    split W (Wq,Wk,Wv,Wo), B-frag order
// ---------------------------------------------------------------------------

// Fused setup: blocks 0..127 pack W; 128..255 build WB; 256..575 zero pads.
__global__ __launch_bounds__(512) void setup_kernel(
    const float* __restrict__ Wq, const float* __restrict__ Wk,
    const float* __restrict__ Wv, const float* __restrict__ Wo,
    const float* __restrict__ pos_bias,
    ushort* __restrict__ Wh, ushort* __restrict__ Wl,
    ushort* __restrict__ WB,
    ushort* __restrict__ ekTF, ushort* __restrict__ ekvTF)
{
    const int b = blockIdx.x;
    const int tid = threadIdx.x;
    if (b < 128) {
        // ---- pack Wq/Wk/Wv/Wo into B-frag order, split hi/lo bf16 ----
        const int id = b;                 // (mat*8+ct)*4+ks
        const int mat = id >> 5;
        const int ct = (id & 31) >> 2, ks = id & 3;
        const int lane = tid >> 3, j = tid & 7;
        const int k = ks * 32 + (lane >> 4) * 8 + j;
        const int col = ct * 16 + (lane & 15);
        const float* W = (mat == 0) ? Wq : ((mat == 1) ? Wk : ((mat == 2) ? Wv : Wo));
        float w = W[k * DM + col];
        ushort h = bf16_rne(w);
        Wh[(size_t)id * 512 + tid] = h;
        Wl[(size_t)id * 512 + tid] = bf16_rne(w - bf16_to_f(h));
    } else if (b < 256) {
        // ---- banded weights in A-frag order per 16-i tile ----
        const int it = b - 128;          // 0..127
        const int i0 = it * 16;
        for (int t = tid; t < 5 * 64 * 8; t += 512) {
            const int ks = t >> 9;
            const int lane = (t >> 3) & 63;
            const int jj = t & 7;
            const int m = lane & 15;
            const int k = ks * 32 + ((lane >> 4) << 3) + jj;
            const int i = i0 + m;
            const int j = i0 - 64 + k;
            const int rel = k - 64 - m;  // j - i
            float val = 0.f;
            if (rel > -WIN && rel < WIN && j >= 0 && j < SL)
                val = __expf(pos_bias[(size_t)i * SL + j]) - 1.f;
            WB[(size_t)it * 2560 + t] = bf16_rne(val);
        }
    } else {
        // ---- zero the pad tiles of ekTF/ekvTF ----
        const int zb = b - 256;          // 0..319 = n*10 + slot
        const int n = zb / 10, slot = zb % 10;
        const int jt_p = (slot < PADF) ? slot : (NT + slot);   // 0..3, 132..137
        const size_t base = ((size_t)n * NTP + jt_p) * 2048 + (size_t)tid * 4;
        ushort4 z; z.x = 0; z.y = 0; z.z = 0; z.w = 0;
        *(ushort4*)&ekTF [base] = z;
        *(ushort4*)&ekvTF[base] = z;
    }
}

// QKV projection via split-bf16 MFMA. Block = (n, 64 l's), 4 waves.
// Epilogue writes sq (fp32) + tiled bf16 ekTF/ekvTF + fp32 partial sums.
__global__ __launch_bounds__(256, 2) void qkv_kernel(
    const float* __restrict__ x,
    const ushort* __restrict__ Wh, const ushort* __restrict__ Wl,
    const float* __restrict__ bq, const float* __restrict__ bk,
    const float* __restrict__ bv,
    float* __restrict__ sq, ushort* __restrict__ ekTF, ushort* __restrict__ ekvTF,
    float* __restrict__ Pk, float* __restrict__ Pkv)
{
    __shared__ ushort Ah[64 * 128];   // frag order: ((lt*4+ks)*64+lane)*8+j
    __shared__ ushort Al[64 * 128];
    const int n = blockIdx.y, bx = blockIdx.x, l0 = bx * 64;
    const int tid = threadIdx.x;

    {
        const int lo = tid & 63;
        const int cq = tid >> 6;
        const int l  = l0 + lo;
        for (int cc = 0; cc < 8; ++cc) {
            const int c0 = cc * 16 + cq * 4;
            float xv[4]; ushort hh[4], ll[4];
            #pragma unroll
            for (int u = 0; u < 4; ++u)
                xv[u] = x[((size_t)n * DM + c0 + u) * SL + l];
            #pragma unroll
            for (int u = 0; u < 4; ++u) {
                hh[u] = bf16_rne(xv[u]);
                ll[u] = bf16_rne(xv[u] - bf16_to_f(hh[u]));
            }
            const int idx = ((lo >> 4) * 4 + (c0 >> 5)) * 512
                          + (((c0 >> 3) & 3) * 16 + (lo & 15)) * 8 + (c0 & 7);
            ushort4 hv; hv.x = hh[0]; hv.y = hh[1]; hv.z = hh[2]; hv.w = hh[3];
            ushort4 lv; lv.x = ll[0]; lv.y = ll[1]; lv.z = ll[2]; lv.w = ll[3];
            *(ushort4*)&Ah[idx] = hv;
            *(ushort4*)&Al[idx] = lv;
        }
    }
    __syncthreads();

    const int wave = tid >> 6;
    const int lane = tid & 63;
    const int dcol = lane & 15;
    const int dbase = wave * 32;

    f32x4 acc[3][2][4];
    #pragma unroll
    for (int dt = 0; dt < 2; ++dt) {
        const int d = dbase + dt * 16 + dcol;
        const float b0 = bq[d], b1 = bk[d], b2 = bv[d];
        #pragma unroll
        for (int lt = 0; lt < 4; ++lt) {
            acc[0][dt][lt] = (f32x4){b0, b0, b0, b0};
            acc[1][dt][lt] = (f32x4){b1, b1, b1, b1};
            acc[2][dt][lt] = (f32x4){b2, b2, b2, b2};
        }
    }

    const bf16x8* WhV = (const bf16x8*)Wh;
    const bf16x8* WlV = (const bf16x8*)Wl;
    #pragma unroll
    for (int ks = 0; ks < 4; ++ks) {
        bf16x8 bh[3][2], bl[3][2];
        #pragma unroll
        for (int m = 0; m < 3; ++m)
            #pragma unroll
            for (int dt = 0; dt < 2; ++dt) {
                const int fi = ((m * 8 + wave * 2 + dt) * 4 + ks) * 64 + lane;
                bh[m][dt] = WhV[fi];
                bl[m][dt] = WlV[fi];
            }
        #pragma unroll
        for (int lt = 0; lt < 4; ++lt) {
            const bf16x8 ah = *(const bf16x8*)&Ah[((lt * 4 + ks) * 64 + lane) * 8];
            const bf16x8 al = *(const bf16x8*)&Al[((lt * 4 + ks) * 64 + lane) * 8];
            #pragma unroll
            for (int m = 0; m < 3; ++m)
                #pragma unroll
                for (int dt = 0; dt < 2; ++dt) {
                    acc[m][dt][lt] = __builtin_amdgcn_mfma_f32_16x16x32_bf16(
                        ah, bh[m][dt], acc[m][dt][lt], 0, 0, 0);
                    acc[m][dt][lt] = __builtin_amdgcn_mfma_f32_16x16x32_bf16(
                        al, bh[m][dt], acc[m][dt][lt], 0, 0, 0);
                    acc[m][dt][lt] = __builtin_amdgcn_mfma_f32_16x16x32_bf16(
                        ah, bl[m][dt], acc[m][dt][lt], 0, 0, 0);
                }
        }
    }

    const int lrow0 = (lane >> 4) * 4;
    float psk[2] = {0.f, 0.f}, pskv[2] = {0.f, 0.f};
    #pragma unroll
    for (int dt = 0; dt < 2; ++dt) {
        const int d = dbase + dt * 16 + dcol;
        #pragma unroll
        for (int lt = 0; lt < 4; ++lt) {
            const f32x4 q4 = acc[0][dt][lt];
            const f32x4 k4 = acc[1][dt][lt];
            const f32x4 v4 = acc[2][dt][lt];
            ushort eh[4], zh[4];
            #pragma unroll
            for (int r = 0; r < 4; ++r) {
                const int l = l0 + lt * 16 + lrow0 + r;
                const float e = __expf(k4[r]);
                const float z = e * v4[r];
                sq[((size_t)n * SL + l) * DM + d] = 1.f / (1.f + __expf(-q4[r]));
                eh[r] = bf16_rne(e);
                zh[r] = bf16_rne(z);
                psk[dt]  += e;
                pskv[dt] += z;
            }
            // tiled store: tile jt = (l0+lt*16)/16, row d, jo = lrow0..lrow0+3
            const size_t tb = ((size_t)n * NTP + PADF + ((l0 + lt * 16) >> 4)) * 2048
                            + (size_t)d * 16 + lrow0;
            ushort4 ev; ev.x = eh[0]; ev.y = eh[1]; ev.z = eh[2]; ev.w = eh[3];
            ushort4 zv; zv.x = zh[0]; zv.y = zh[1]; zv.z = zh[2]; zv.w = zh[3];
            *(ushort4*)&ekTF [tb] = ev;
            *(ushort4*)&ekvTF[tb] = zv;
        }
    }
    #pragma unroll
    for (int dt = 0; dt < 2; ++dt) {
        float a = psk[dt], b = pskv[dt];
        a += __shfl_xor(a, 16, 64); a += __shfl_xor(a, 32, 64);
        b += __shfl_xor(b, 16, 64); b += __shfl_xor(b, 32, 64);
        if ((lane >> 4) == 0) {
            const size_t o = ((size_t)n * 32 + bx) * DM + dbase + dt * 16 + dcol;
            Pk [o] = a;
            Pkv[o] = b;
        }
    }
}

// Reduce the 32 per-block segments to full-L sums.
__global__ __launch_bounds__(128) void totals_final(
    const float* __restrict__ Pk, const float* __restrict__ Pkv,
    float* __restrict__ Sk, float* __restrict__ Skv)
{
    const int n = blockIdx.x;
    const int d = threadIdx.x;
    float sk = 0.f, skv = 0.f;
    #pragma unroll
    for (int seg = 0; seg < 32; ++seg) {
        sk  += Pk [(n * 32 + seg) * DM + d];
        skv += Pkv[(n * 32 + seg) * DM + d];
    }
    Sk [n * DM + d] = sk;
    Skv[n * DM + d] = skv;
}

// FUSED band correction + output projection, wave-local handoff.
// Phase-1 B loads now read the tiled ekTF/ekvTF layout: each load is two
// fully-used contiguous 512-B regions (8 cache lines, 100% utilization).
__global__ __launch_bounds__(256, 4) void band_out_kernel(
    const ushort* __restrict__ ekTF, const ushort* __restrict__ ekvTF,
    const ushort* __restrict__ WB,
    const float* __restrict__ Sk, const float* __restrict__ Skv,
    const float* __restrict__ sqg,
    const ushort* __restrict__ Wh, const ushort* __restrict__ Wl,
    const float* __restrict__ bo, float* __restrict__ out)
{
    __shared__ __align__(16) union {
        float ylds[64 * YST];   // y fp32, [row l_local][col d]
        float ot[128 * 65];     // out transpose buffer [c][l_local]
    } u;

    const int bid = blockIdx.x;          // 0..1023
    const int xcd = bid & 7;
    const int slot = bid >> 3;           // 0..127
    const int nsub = slot >> 5;          // 0..3
    const int itg  = slot & 31;          // 0..31
    const int n = xcd * 4 + nsub;        // 4 n's per XCD
    const int wave = threadIdx.x >> 6;
    const int lane = threadIdx.x & 63;
    const int it = itg * 4 + wave;       // 0..127
    const int i0 = it * 16;
    const int l0 = itg * 64;

    const int dcol = lane & 15;
    const int jgrp8 = (lane >> 4) << 3;

    // ---- Phase 1: banded MFMA over tiled layout ----
    f32x4 den[8], num[8];
    #pragma unroll
    for (int dt = 0; dt < 8; ++dt) {
        const float sk = Sk [n * DM + dt * 16 + dcol];
        const float sv = Skv[n * DM + dt * 16 + dcol];
        den[dt] = (f32x4){sk, sk, sk, sk};
        num[dt] = (f32x4){sv, sv, sv, sv};
    }

    const bf16x8* WBv = (const bf16x8*)(WB + (size_t)it * 2560);
    // lane-dependent tile select: jt_p = it + 2ks + (lane>>5); jo = ((lane>>4)&1)*8
    const size_t lsel = (size_t)(lane >> 5) * 2048 + (size_t)((lane >> 4) & 1) * 8
                      + (size_t)dcol * 16;
    #pragma unroll
    for (int ks = 0; ks < 5; ++ks) {
        const bf16x8 a = WBv[ks * 64 + lane];
        const size_t tb = ((size_t)n * NTP + it + 2 * ks) * 2048 + lsel;
        #pragma unroll
        for (int dt = 0; dt < 8; ++dt) {
            const size_t rbase = tb + (size_t)dt * 256;   // dt*16 rows * 16 jo
            const bf16x8 bden = *(const bf16x8*)(ekTF  + rbase);
            const bf16x8 bnum = *(const bf16x8*)(ekvTF + rbase);
            den[dt] = __builtin_amdgcn_mfma_f32_16x16x32_bf16(a, bden, den[dt], 0, 0, 0);
            num[dt] = __builtin_amdgcn_mfma_f32_16x16x32_bf16(a, bnum, num[dt], 0, 0, 0);
        }
    }

    // Gate with sigmoid(q); write fp32 y into this wave's own LDS stripe.
    const int irow0 = (lane >> 4) << 2;
    #pragma unroll
    for (int dt = 0; dt < 8; ++dt) {
        const int d = dt * 16 + dcol;
        #pragma unroll
        for (int r = 0; r < 4; ++r) {
            const int i = i0 + irow0 + r;
            const float s = sqg[((size_t)n * SL + i) * DM + d];
            const float y = s * num[dt][r] / den[dt][r];
            u.ylds[(wave * 16 + irow0 + r) * YST + d] = y;
        }
    }

    // ---- Handoff: read own stripe in A-octet order (wave-coherent) ----
    float af[4][8];
    {
        const int arow = wave * 16 + (lane & 15);
        #pragma unroll
        for (int ks = 0; ks < 4; ++ks) {
            const int base = arow * YST + ks * 32 + jgrp8;
            const float4 a0 = *(const float4*)&u.ylds[base];
            const float4 a1 = *(const float4*)&u.ylds[base + 4];
            af[ks][0] = a0.x; af[ks][1] = a0.y; af[ks][2] = a0.z; af[ks][3] = a0.w;
            af[ks][4] = a1.x; af[ks][5] = a1.y; af[ks][6] = a1.z; af[ks][7] = a1.w;
        }
    }
    __syncthreads();   // all waves done with ylds; ot may now overwrite

    bf16x8 yh[4], yl[4];
    #pragma unroll
    for (int ks = 0; ks < 4; ++ks) {
        #pragma unroll
        for (int t = 0; t < 8; ++t) {
            const float v = af[ks][t];
            const ushort h = bf16_rne(v);
            yh[ks][t] = (short)h;
            yl[ks][t] = (short)bf16_rne(v - bf16_to_f(h));
        }
    }

    // ---- Phase 2: out projection, own 16 rows x all 128 c ----
    f32x4 acc[8];
    #pragma unroll
    for (int ct = 0; ct < 8; ++ct) {
        const float b0 = bo[ct * 16 + dcol];
        acc[ct] = (f32x4){b0, b0, b0, b0};
    }

    const bf16x8* WhV = (const bf16x8*)Wh;
    const bf16x8* WlV = (const bf16x8*)Wl;
    #pragma unroll
    for (int ks = 0; ks < 4; ++ks) {
        #pragma unroll
        for (int ct = 0; ct < 8; ++ct) {
            const int fi = ((24 + ct) * 4 + ks) * 64 + lane;  // mat=3 (Wo)
            const bf16x8 bh = WhV[fi];
            const bf16x8 bl = WlV[fi];
            acc[ct] = __builtin_amdgcn_mfma_f32_16x16x32_bf16(yh[ks], bh, acc[ct], 0, 0, 0);
            acc[ct] = __builtin_amdgcn_mfma_f32_16x16x32_bf16(yl[ks], bh, acc[ct], 0, 0, 0);
            acc[ct] = __builtin_amdgcn_mfma_f32_16x16x32_bf16(yh[ks], bl, acc[ct], 0, 0, 0);
        }
    }

    // Transpose through LDS: ot[c][l_local]; C rows = wave's 16 l's.
    #pragma unroll
    for (int ct = 0; ct < 8; ++ct) {
        const int c = ct * 16 + dcol;
        #pragma unroll
        for (int r = 0; r < 4; ++r)
            u.ot[c * 65 + wave * 16 + irow0 + r] = acc[ct][r];
    }
    __syncthreads();

    // Coalesced store: 64 contiguous floats per c row.
    const int tid = threadIdx.x;
    #pragma unroll
    for (int rep = 0; rep < 32; ++rep) {
        const int e = rep * 256 + tid;
        const int c = e >> 6, l = e & 63;
        out[((size_t)n * DM + c) * SL + l0 + l] = u.ot[c * 65 + l];
    }
}

extern "C" void kernel_launch(void* const* d_in, const int* in_sizes, int n_in,
                              void* d_out, int out_size, void* d_ws, size_t ws_size,
                              hipStream_t stream)
{
    const float* x        = (const float*)d_in[0];
    const float* Wq       = (const float*)d_in[1];
    const float* bq       = (const float*)d_in[2];
    const float* Wk       = (const float*)d_in[3];
    const float* bk       = (const float*)d_in[4];
    const float* Wv       = (const float*)d_in[5];
    const float* bv       = (const float*)d_in[6];
    const float* Wo       = (const float*)d_in[7];
    const float* bo       = (const float*)d_in[8];
    const float* pos_bias = (const float*)d_in[9];
    float* out = (float*)d_out;

    float* ws  = (float*)d_ws;
    const size_t NLD = (size_t)NB * SL * DM;
    float*  sq    = ws;
    ushort* ekTF  = (ushort*)(sq + NLD);
    ushort* ekvTF = ekTF  + (size_t)NB * NTP * 2048;
    ushort* WB    = ekvTF + (size_t)NB * NTP * 2048;
    float*  Sk    = (float*)(WB + (size_t)128 * 2560);
    float*  Skv   = Sk   + (size_t)NB * DM;
    float*  Pk    = Skv  + (size_t)NB * DM;
    float*  Pkv   = Pk   + (size_t)NB * 32 * DM;
    ushort* Wh    = (ushort*)(Pkv + (size_t)NB * 32 * DM);
    ushort* Wl    = Wh + (size_t)4 * DM * DM;

    setup_kernel   <<<dim3(576),     512, 0, stream>>>(Wq, Wk, Wv, Wo, pos_bias,
                                                       Wh, Wl, WB, ekTF, ekvTF);
    qkv_kernel     <<<dim3(32, NB),  256, 0, stream>>>(x, Wh, Wl, bq, bk, bv,
                                                       sq, ekTF, ekvTF, Pk, Pkv);
    totals_final   <<<dim3(NB),      128, 0, stream>>>(Pk, Pkv, Sk, Skv);
    band_out_kernel<<<dim3(NB * 32), 256, 0, stream>>>(ekTF, ekvTF, WB, Sk, Skv, sq,
                                                       Wh, Wl, bo, out);
}